// Round 1
// 585.921 us; speedup vs baseline: 1.1616x; 1.1616x over previous
//
#include <hip/hip_runtime.h>
#include <stdint.h>

// Problem constants: B=8, Cin=Cout=256, H=W=64, H2=W2=128, P=4 points.
#define NB   8
#define CH   256
#define HW0  4096    // 64*64
#define HW2  16384   // 128*128

typedef __attribute__((ext_vector_type(8))) short short8;
typedef __attribute__((ext_vector_type(8))) unsigned short u16x8;
typedef __attribute__((ext_vector_type(4))) unsigned short u16x4;
typedef __attribute__((ext_vector_type(4))) float floatx4;

__device__ inline unsigned short f2bf(float f) {
    union { float f; uint32_t u; } v; v.f = f;
    return (unsigned short)((v.u + 0x7FFFu + ((v.u >> 16) & 1u)) >> 16);
}
__device__ inline float bf2f(unsigned short h) {
    union { uint32_t u; float f; } v; v.u = ((uint32_t)h) << 16;
    return v.f;
}

// ---------------------------------------------------------------------------
// ktrans: [B][256][M] f32  ->  [B][M][256] bf16   (transpose + convert)
// ---------------------------------------------------------------------------
__global__ __launch_bounds__(256) void ktrans(const float* __restrict__ src,
        unsigned short* __restrict__ dst, int M) {
    const int b = blockIdx.z, k0 = blockIdx.y * 32, m0 = blockIdx.x * 128;
    const int tid = threadIdx.x;
    __shared__ unsigned short tile[32][132];
    const float* s = src + ((size_t)b * CH + k0) * M + m0;
    for (int c = tid; c < 1024; c += 256) {
        int kk = c >> 5, mm = (c & 31) * 4;
        float4 v = *(const float4*)(s + (size_t)kk * M + mm);
        u16x4 o = { f2bf(v.x), f2bf(v.y), f2bf(v.z), f2bf(v.w) };
        *(u16x4*)&tile[kk][mm] = o;
    }
    __syncthreads();
    unsigned short* d = dst + ((size_t)b * M + m0) * CH + k0;
    for (int c = tid; c < 512; c += 256) {
        int mm = c >> 2, kc = (c & 3) * 8;
        u16x8 v;
        #pragma unroll
        for (int i = 0; i < 8; ++i) v[i] = tile[kc + i][mm];
        *(u16x8*)(d + (size_t)mm * CH + kc) = v;
    }
}

// ---------------------------------------------------------------------------
// kwconv: pack weights to bf16.  A1[512][256]: rows 0-255 = W1a, 256-511 = Wf.
// A2[256][256] = W1b.
// ---------------------------------------------------------------------------
__global__ __launch_bounds__(256) void kwconv(const float* __restrict__ W1,
        const float* __restrict__ Wf, unsigned short* __restrict__ A1,
        unsigned short* __restrict__ A2) {
    int i = blockIdx.x * 256 + threadIdx.x;
    if (i < 512 * 256) {
        int n = i >> 8, k = i & 255;
        float v = (n < 256) ? W1[n * 512 + k] : Wf[(size_t)(n - 256) * 256 + k];
        A1[i] = f2bf(v);
    }
    if (i < 256 * 256) {
        int n = i >> 8, k = i & 255;
        A2[i] = f2bf(W1[n * 512 + 256 + k]);
    }
}

// ---------------------------------------------------------------------------
// kwpack: W2 [8][256][3][3] f32 -> W3p [9 taps][16 o (8 padded)][256 ci] bf16
// Launched AFTER k1 (reuses the then-dead highT buffer).
// ---------------------------------------------------------------------------
__global__ __launch_bounds__(256) void kwpack(const float* __restrict__ W2v,
        unsigned short* __restrict__ W3p) {
    int i = blockIdx.x * 256 + threadIdx.x;   // 9*16*256 = 36864
    if (i >= 9 * 16 * 256) return;
    int ci = i & 255, o = (i >> 8) & 15, t = i >> 12;
    float v = (o < 8) ? W2v[((size_t)o * 256 + ci) * 9 + t] : 0.0f;
    W3p[i] = f2bf(v);
}

// ---------------------------------------------------------------------------
// K1: dual MFMA GEMM:  D[n,m] = A1[n,:] . highT[m,:]   (k-contig both sides)
//   n<256 -> T[b][n][m] ; n>=256 -> proc[b][n-256][m] + bf
// Tile 128(n) x 128(m), 4 waves of 64x64, 16x16x32 bf16 MFMA.
// ---------------------------------------------------------------------------
__global__ __launch_bounds__(256) void k1_mfma(
    const unsigned short* __restrict__ highT,  // [B][4096][256]
    const unsigned short* __restrict__ A1,     // [512][256]
    const float* __restrict__ bfv,
    float* __restrict__ T, float* __restrict__ proc)
{
    const int b = blockIdx.z;
    const int m0 = blockIdx.x * 128;   // over 4096
    const int n0 = blockIdx.y * 128;   // over 512
    const int tid = threadIdx.x;
    __shared__ unsigned short As[128 * 40];
    __shared__ unsigned short Xs[128 * 40];
    const int lane = tid & 63, wid = tid >> 6;
    const int wn = (wid >> 1) * 64, wm = (wid & 1) * 64;
    const int l15 = lane & 15, quad = lane >> 4;

    floatx4 acc[4][4];
    #pragma unroll
    for (int i = 0; i < 4; ++i)
        #pragma unroll
        for (int j = 0; j < 4; ++j)
            acc[i][j] = (floatx4){0.f, 0.f, 0.f, 0.f};

    const unsigned short* Xg = highT + ((size_t)b * HW0 + m0) * CH;

    for (int k0 = 0; k0 < 256; k0 += 32) {
        for (int c = tid; c < 512; c += 256) {
            int row = c >> 2, kc = (c & 3) * 8;
            *(u16x8*)&As[row * 40 + kc] =
                *(const u16x8*)(A1 + (size_t)(n0 + row) * CH + k0 + kc);
            *(u16x8*)&Xs[row * 40 + kc] =
                *(const u16x8*)(Xg + (size_t)row * CH + k0 + kc);
        }
        __syncthreads();
        short8 af[4], bfr[4];
        #pragma unroll
        for (int i = 0; i < 4; ++i)
            af[i] = *(const short8*)&As[(wn + i * 16 + l15) * 40 + quad * 8];
        #pragma unroll
        for (int j = 0; j < 4; ++j)
            bfr[j] = *(const short8*)&Xs[(wm + j * 16 + l15) * 40 + quad * 8];
        #pragma unroll
        for (int i = 0; i < 4; ++i)
            #pragma unroll
            for (int j = 0; j < 4; ++j)
                acc[i][j] = __builtin_amdgcn_mfma_f32_16x16x32_bf16(
                    af[i], bfr[j], acc[i][j], 0, 0, 0);
        __syncthreads();
    }

    const bool isT = (n0 < 256);
    #pragma unroll
    for (int i = 0; i < 4; ++i) {
        int nb = n0 + wn + i * 16 + quad * 4;
        #pragma unroll
        for (int r = 0; r < 4; ++r) {
            int n = nb + r;
            #pragma unroll
            for (int j = 0; j < 4; ++j) {
                int m = m0 + wm + j * 16 + l15;
                float v = acc[i][j][r];
                if (isT) T[((size_t)b * CH + n) * HW0 + m] = v;
                else proc[((size_t)b * CH + n - 256) * HW0 + m] = v + bfv[n - 256];
            }
        }
    }
}

// ---------------------------------------------------------------------------
// K2: MFMA GEMM + fused upsample epilogue:
//   val[n, y, x] = relu( A2[n,:].lowT[m,:] + up2x(T)[n,y,x] + b1[n] )
// Written TRANSPOSED as off_featT[b][pix][256] bf16 via LDS transpose
// (k-contiguous layout for K3's MFMA conv).
// Block covers one output row y (m0 = y*128).  Grid (128, 2, B).
// ---------------------------------------------------------------------------
__global__ __launch_bounds__(256) void k2_mfma(
    const unsigned short* __restrict__ lowT,   // [B][16384][256]
    const unsigned short* __restrict__ A2,     // [256][256]
    const float* __restrict__ b1, const float* __restrict__ T,
    unsigned short* __restrict__ off_featT)
{
    const int b = blockIdx.z;
    const int m0 = blockIdx.x * 128;   // over 16384; y = blockIdx.x
    const int n0 = blockIdx.y * 128;   // over 256
    const int tid = threadIdx.x;
    __shared__ unsigned short smem[2 * 128 * 40];
    unsigned short* As = smem;
    unsigned short* Xs = smem + 128 * 40;
    const int lane = tid & 63, wid = tid >> 6;
    const int wn = (wid >> 1) * 64, wm = (wid & 1) * 64;
    const int l15 = lane & 15, quad = lane >> 4;

    floatx4 acc[4][4];
    #pragma unroll
    for (int i = 0; i < 4; ++i)
        #pragma unroll
        for (int j = 0; j < 4; ++j)
            acc[i][j] = (floatx4){0.f, 0.f, 0.f, 0.f};

    const unsigned short* Xg = lowT + ((size_t)b * HW2 + m0) * CH;

    for (int k0 = 0; k0 < 256; k0 += 32) {
        for (int c = tid; c < 512; c += 256) {
            int row = c >> 2, kc = (c & 3) * 8;
            *(u16x8*)&As[row * 40 + kc] =
                *(const u16x8*)(A2 + (size_t)(n0 + row) * CH + k0 + kc);
            *(u16x8*)&Xs[row * 40 + kc] =
                *(const u16x8*)(Xg + (size_t)row * CH + k0 + kc);
        }
        __syncthreads();
        short8 af[4], bfr[4];
        #pragma unroll
        for (int i = 0; i < 4; ++i)
            af[i] = *(const short8*)&As[(wn + i * 16 + l15) * 40 + quad * 8];
        #pragma unroll
        for (int j = 0; j < 4; ++j)
            bfr[j] = *(const short8*)&Xs[(wm + j * 16 + l15) * 40 + quad * 8];
        #pragma unroll
        for (int i = 0; i < 4; ++i)
            #pragma unroll
            for (int j = 0; j < 4; ++j)
                acc[i][j] = __builtin_amdgcn_mfma_f32_16x16x32_bf16(
                    af[i], bfr[j], acc[i][j], 0, 0, 0);
        __syncthreads();
    }

    // epilogue: upsample taps. y uniform per block.
    const int y = blockIdx.x;
    int hk = y >> 1;
    int yA, yB; float wyA, wyB;
    if (y & 1) { yA = hk; yB = min(hk + 1, 63); wyA = 0.75f; wyB = 0.25f; }
    else       { yB = hk; yA = max(hk - 1, 0);  wyA = 0.25f; wyB = 0.75f; }

    int xA[4], xB[4]; float wxA[4], wxB[4];
    #pragma unroll
    for (int j = 0; j < 4; ++j) {
        int x = wm + j * 16 + l15;
        int xk = x >> 1;
        if (x & 1) { xA[j] = xk; xB[j] = min(xk + 1, 63); wxA[j] = 0.75f; wxB[j] = 0.25f; }
        else       { xB[j] = xk; xA[j] = max(xk - 1, 0);  wxA[j] = 0.25f; wxB[j] = 0.75f; }
    }

    // compute final (relu'd) values in place
    #pragma unroll
    for (int i = 0; i < 4; ++i) {
        int nb = n0 + wn + i * 16 + quad * 4;
        #pragma unroll
        for (int r = 0; r < 4; ++r) {
            int n = nb + r;
            const float* tb  = T + ((size_t)b * CH + n) * HW0;
            const float* trA = tb + yA * 64;
            const float* trB = tb + yB * 64;
            float bias = b1[n];
            #pragma unroll
            for (int j = 0; j < 4; ++j) {
                float up = wyA * (wxA[j] * trA[xA[j]] + wxB[j] * trA[xB[j]])
                         + wyB * (wxA[j] * trB[xA[j]] + wxB[j] * trB[xB[j]]);
                acc[i][j][r] = fmaxf(acc[i][j][r] + up + bias, 0.0f);
            }
        }
    }

    // LDS transpose: two passes of [64 x][128 n], write k-contiguous bf16.
    unsigned short (*tile)[136] = (unsigned short (*)[136])smem;
    for (int xh = 0; xh < 2; ++xh) {
        __syncthreads();
        if ((wid & 1) == xh) {
            #pragma unroll
            for (int i = 0; i < 4; ++i) {
                int nc = wn + i * 16 + quad * 4;
                #pragma unroll
                for (int j = 0; j < 4; ++j) {
                    int xr = j * 16 + l15;
                    unsigned int lo = (unsigned int)f2bf(acc[i][j][0])
                                    | ((unsigned int)f2bf(acc[i][j][1]) << 16);
                    unsigned int hi = (unsigned int)f2bf(acc[i][j][2])
                                    | ((unsigned int)f2bf(acc[i][j][3]) << 16);
                    *(unsigned int*)&tile[xr][nc]     = lo;
                    *(unsigned int*)&tile[xr][nc + 2] = hi;
                }
            }
        }
        __syncthreads();
        for (int c = tid; c < 1024; c += 256) {
            int xr = c >> 4, nc = (c & 15) * 8;
            u16x8 v = *(u16x8*)&tile[xr][nc];
            *(u16x8*)(off_featT +
                ((size_t)b * HW2 + (size_t)y * 128 + xh * 64 + xr) * CH + n0 + nc) = v;
        }
    }
}

// ---------------------------------------------------------------------------
// K3: offsets = conv3x3(off_featT, W3p) via MFMA.
// Block = one row y (128 px), all 8 out channels (padded to 16), full K=2304.
// 4 waves x 32 px each. A-frag = pixels (k-contig off_featT), B-frag = W3p.
// No split-K, no atomics, no memset.
// ---------------------------------------------------------------------------
__global__ __launch_bounds__(256) void k3_mfma(
    const unsigned short* __restrict__ offT,   // [B][16384][256] bf16
    const unsigned short* __restrict__ W3p,    // [9][16][256] bf16
    float* __restrict__ offs)
{
    const int b = blockIdx.y;
    const int y = blockIdx.x;          // 0..127
    const int tid = threadIdx.x;
    const int lane = tid & 63, w = tid >> 6;
    const int l15 = lane & 15, quad = lane >> 4;

    floatx4 acc[2];
    acc[0] = (floatx4){0.f, 0.f, 0.f, 0.f};
    acc[1] = (floatx4){0.f, 0.f, 0.f, 0.f};

    const unsigned short* xb = offT + (size_t)b * HW2 * CH;
    const int xbase = w * 32 + l15;

    for (int k0 = 0; k0 < 256; k0 += 32) {
        #pragma unroll
        for (int t = 0; t < 9; ++t) {
            const int dy = t / 3 - 1, dx = t % 3 - 1;
            const int yy = y + dy;
            if ((unsigned)yy >= 128u) continue;   // uniform: zero-pad row
            short8 bw = *(const short8*)(W3p + (size_t)(t * 16 + l15) * CH
                                         + k0 + quad * 8);
            const unsigned short* rowp = xb + ((size_t)yy * 128) * CH + k0 + quad * 8;
            #pragma unroll
            for (int j = 0; j < 2; ++j) {
                int xx = xbase + j * 16 + dx;
                short8 ax = (short8){0, 0, 0, 0, 0, 0, 0, 0};
                if ((unsigned)xx < 128u)
                    ax = *(const short8*)(rowp + (size_t)xx * CH);
                acc[j] = __builtin_amdgcn_mfma_f32_16x16x32_bf16(
                    ax, bw, acc[j], 0, 0, 0);
            }
        }
    }

    // D: col(l15)=out channel, row(quad*4+r)=pixel within fragment
    if (l15 < 8) {
        float* ob = offs + ((size_t)b * 8 + l15) * HW2 + (size_t)y * 128;
        #pragma unroll
        for (int j = 0; j < 2; ++j) {
            int xpix = w * 32 + j * 16 + quad * 4;
            *(floatx4*)(ob + xpix) = acc[j];
        }
    }
}

// ---------------------------------------------------------------------------
// K4: deformable 4-point border-clamped bilinear sample of proc (64x64),
// averaged.  b2 bias folded in when reading raw offsets.
// ---------------------------------------------------------------------------
__global__ __launch_bounds__(256) void k4_sample(
    const float* __restrict__ offs, const float* __restrict__ b2v,
    const float* __restrict__ proc, float* __restrict__ out)
{
    const int bz = blockIdx.z;
    const int b = bz >> 2, cq = bz & 3;
    const int y = blockIdx.y;
    const int xt = blockIdx.x;   // 0..1
    const int tid = threadIdx.x;

    __shared__ int   sx0[4][64], sy0[4][64];
    __shared__ float sfx[4][64], sfy[4][64];

    if (tid < 64) {
        int x = xt * 64 + tid;
        float gxb = (2.0f * x) / 127.0f - 1.0f;
        float gyb = (2.0f * y) / 127.0f - 1.0f;
        const float* ob = offs + (size_t)b * 8 * HW2 + y * 128 + x;
        #pragma unroll
        for (int p = 0; p < 4; ++p) {
            float ox = ob[(2 * p) * HW2] + b2v[2 * p];
            float oy = ob[(2 * p + 1) * HW2] + b2v[2 * p + 1];
            float gx = gxb + ox * (2.0f / 128.0f);
            float gy = gyb + oy * (2.0f / 128.0f);
            float gxp = fminf(fmaxf((gx + 1.0f) * 32.0f - 0.5f, 0.0f), 63.0f);
            float gyp = fminf(fmaxf((gy + 1.0f) * 32.0f - 0.5f, 0.0f), 63.0f);
            float x0 = floorf(gxp), y0f = floorf(gyp);
            sx0[p][tid] = (int)x0;
            sy0[p][tid] = (int)y0f;
            sfx[p][tid] = gxp - x0;
            sfy[p][tid] = gyp - y0f;
        }
    }
    __syncthreads();

    const int xl = tid & 63;
    const int cl = tid >> 6;
    const int x = xt * 64 + xl;

    int px0[4], py0[4]; float pfx[4], pfy[4];
    #pragma unroll
    for (int p = 0; p < 4; ++p) {
        px0[p] = sx0[p][xl]; py0[p] = sy0[p][xl];
        pfx[p] = sfx[p][xl]; pfy[p] = sfy[p][xl];
    }

    #pragma unroll 4
    for (int i = 0; i < 16; ++i) {
        int c = cq * 64 + i * 4 + cl;
        const float* pb = proc + ((size_t)b * CH + c) * HW0;
        float acc = 0.f;
        #pragma unroll
        for (int p = 0; p < 4; ++p) {
            int x0 = px0[p], y0i = py0[p];
            int x1 = min(x0 + 1, 63), y1 = min(y0i + 1, 63);
            float fx = pfx[p], fy = pfy[p];
            float v00 = pb[y0i * 64 + x0];
            float v01 = pb[y0i * 64 + x1];
            float v10 = pb[y1 * 64 + x0];
            float v11 = pb[y1 * 64 + x1];
            float top = v00 + fx * (v01 - v00);
            float bot = v10 + fx * (v11 - v10);
            acc += top + fy * (bot - top);
        }
        out[(((size_t)b * CH + c) * 128 + y) * 128 + x] = acc * 0.25f;
    }
}

// ---------------------------------------------------------------------------
extern "C" void kernel_launch(void* const* d_in, const int* in_sizes, int n_in,
                              void* d_out, int out_size, void* d_ws, size_t ws_size,
                              hipStream_t stream) {
    const float* high = (const float*)d_in[0];
    const float* low  = (const float*)d_in[1];
    const float* W1   = (const float*)d_in[2];
    const float* b1   = (const float*)d_in[3];
    const float* W2v  = (const float*)d_in[4];
    const float* b2v  = (const float*)d_in[5];
    const float* Wf   = (const float*)d_in[6];
    const float* bfv  = (const float*)d_in[7];
    float* out = (float*)d_out;
    float* ws  = (float*)d_ws;

    // ws layout (floats):
    float* T    = ws;                       // 8*256*4096  = 8388608
    float* proc = ws + 8388608;             // 8388608
    float* offs = ws + 16777216;            // 1048576
    unsigned short* highT = (unsigned short*)(ws + 17825792);  // 8388608 shorts
    unsigned short* A1 = highT + 8388608;   // 131072 shorts
    unsigned short* A2 = A1 + 131072;       // 65536 shorts  (total ~88.5 MB)

    // W3p reuses highT's storage — written only AFTER k1 (highT dead by then).
    unsigned short* W3p = highT;            // 36864 shorts

    // d_out (33554432 floats = 134 MB) doubles as scratch:
    unsigned short* lowT      = (unsigned short*)out;              // 33554432 shorts
    unsigned short* off_featT = ((unsigned short*)out) + 33554432; // 33554432 shorts

    // transpose+convert inputs to bf16 [b][m][k]
    ktrans<<<dim3(32, 8, NB), 256, 0, stream>>>(high, highT, HW0);
    ktrans<<<dim3(128, 8, NB), 256, 0, stream>>>(low, lowT, HW2);
    kwconv<<<dim3(512), 256, 0, stream>>>(W1, Wf, A1, A2);

    // T = W1a@high, proc = Wf@high + bf     (bf16 MFMA)
    k1_mfma<<<dim3(32, 4, NB), 256, 0, stream>>>(highT, A1, bfv, T, proc);
    // pack conv3x3 weights (over dead highT region)
    kwpack<<<dim3(144), 256, 0, stream>>>(W2v, W3p);
    // off_featT = relu(W1b@low + up2x(T) + b1)  -> bf16 [b][pix][256]
    k2_mfma<<<dim3(128, 2, NB), 256, 0, stream>>>(lowT, A2, b1, T, off_featT);
    // offs = conv3x3(off_featT, W2)  (MFMA, full-K per block, no atomics)
    k3_mfma<<<dim3(128, NB), 256, 0, stream>>>(off_featT, W3p, offs);
    // out = mean over 4 deformable bilinear samples of proc
    k4_sample<<<dim3(2, 128, NB * 4), 256, 0, stream>>>(offs, b2v, proc, out);
}

// Round 3
// 550.999 us; speedup vs baseline: 1.2352x; 1.0634x over previous
//
#include <hip/hip_runtime.h>
#include <stdint.h>

// Problem constants: B=8, Cin=Cout=256, H=W=64, H2=W2=128, P=4 points.
#define NB   8
#define CH   256
#define HW0  4096    // 64*64
#define HW2  16384   // 128*128

typedef __attribute__((ext_vector_type(8))) short short8;
typedef __attribute__((ext_vector_type(8))) unsigned short u16x8;
typedef __attribute__((ext_vector_type(4))) unsigned short u16x4;
typedef __attribute__((ext_vector_type(4))) float floatx4;

__device__ inline unsigned short f2bf(float f) {
    union { float f; uint32_t u; } v; v.f = f;
    return (unsigned short)((v.u + 0x7FFFu + ((v.u >> 16) & 1u)) >> 16);
}
__device__ inline float bf2f(unsigned short h) {
    union { uint32_t u; float f; } v; v.u = ((uint32_t)h) << 16;
    return v.f;
}

// ---------------------------------------------------------------------------
// ktrans: [B][256][M] f32  ->  [B][M][256] bf16   (transpose + convert)
// ---------------------------------------------------------------------------
__global__ __launch_bounds__(256) void ktrans(const float* __restrict__ src,
        unsigned short* __restrict__ dst, int M) {
    const int b = blockIdx.z, k0 = blockIdx.y * 32, m0 = blockIdx.x * 128;
    const int tid = threadIdx.x;
    __shared__ unsigned short tile[32][132];
    const float* s = src + ((size_t)b * CH + k0) * M + m0;
    for (int c = tid; c < 1024; c += 256) {
        int kk = c >> 5, mm = (c & 31) * 4;
        float4 v = *(const float4*)(s + (size_t)kk * M + mm);
        u16x4 o = { f2bf(v.x), f2bf(v.y), f2bf(v.z), f2bf(v.w) };
        *(u16x4*)&tile[kk][mm] = o;
    }
    __syncthreads();
    unsigned short* d = dst + ((size_t)b * M + m0) * CH + k0;
    for (int c = tid; c < 512; c += 256) {
        int mm = c >> 2, kc = (c & 3) * 8;
        u16x8 v;
        #pragma unroll
        for (int i = 0; i < 8; ++i) v[i] = tile[kc + i][mm];
        *(u16x8*)(d + (size_t)mm * CH + kc) = v;
    }
}

// ---------------------------------------------------------------------------
// kwconv: pack weights to bf16.  A1[512][256]: rows 0-255 = W1a, 256-511 = Wf.
// A2[256][256] = W1b.
// ---------------------------------------------------------------------------
__global__ __launch_bounds__(256) void kwconv(const float* __restrict__ W1,
        const float* __restrict__ Wf, unsigned short* __restrict__ A1,
        unsigned short* __restrict__ A2) {
    int i = blockIdx.x * 256 + threadIdx.x;
    if (i < 512 * 256) {
        int n = i >> 8, k = i & 255;
        float v = (n < 256) ? W1[n * 512 + k] : Wf[(size_t)(n - 256) * 256 + k];
        A1[i] = f2bf(v);
    }
    if (i < 256 * 256) {
        int n = i >> 8, k = i & 255;
        A2[i] = f2bf(W1[n * 512 + 256 + k]);
    }
}

// ---------------------------------------------------------------------------
// kwpack: W2 [8][256][3][3] f32 -> W3p [9 taps][16 o (8 padded)][256 ci] bf16
// Launched AFTER k1 (reuses the then-dead highT buffer).
// ---------------------------------------------------------------------------
__global__ __launch_bounds__(256) void kwpack(const float* __restrict__ W2v,
        unsigned short* __restrict__ W3p) {
    int i = blockIdx.x * 256 + threadIdx.x;   // 9*16*256 = 36864
    if (i >= 9 * 16 * 256) return;
    int ci = i & 255, o = (i >> 8) & 15, t = i >> 12;
    float v = (o < 8) ? W2v[((size_t)o * 256 + ci) * 9 + t] : 0.0f;
    W3p[i] = f2bf(v);
}

// ---------------------------------------------------------------------------
// K1: dual MFMA GEMM:  D[n,m] = A1[n,:] . highT[m,:]   (k-contig both sides)
//   n<256 -> T[b][n][m]  (row-major, consumed by K2's upsample taps)
//   n>=256 -> procT[b][m][n-256] + bf   (TRANSPOSED via LDS; channel-contig
//             layout consumed by K4's coalesced gather)
// Tile 128(n) x 128(m), 4 waves of 64x64, 16x16x32 bf16 MFMA.
// ---------------------------------------------------------------------------
__global__ __launch_bounds__(256) void k1_mfma(
    const unsigned short* __restrict__ highT,  // [B][4096][256]
    const unsigned short* __restrict__ A1,     // [512][256]
    const float* __restrict__ bfv,
    float* __restrict__ T, float* __restrict__ procT)
{
    const int b = blockIdx.z;
    const int m0 = blockIdx.x * 128;   // over 4096
    const int n0 = blockIdx.y * 128;   // over 512
    const int tid = threadIdx.x;
    __shared__ __attribute__((aligned(16))) unsigned short smem[2 * 128 * 40];
    unsigned short* As = smem;
    unsigned short* Xs = smem + 128 * 40;
    const int lane = tid & 63, wid = tid >> 6;
    const int wn = (wid >> 1) * 64, wm = (wid & 1) * 64;
    const int l15 = lane & 15, quad = lane >> 4;

    floatx4 acc[4][4];
    #pragma unroll
    for (int i = 0; i < 4; ++i)
        #pragma unroll
        for (int j = 0; j < 4; ++j)
            acc[i][j] = (floatx4){0.f, 0.f, 0.f, 0.f};

    const unsigned short* Xg = highT + ((size_t)b * HW0 + m0) * CH;

    for (int k0 = 0; k0 < 256; k0 += 32) {
        for (int c = tid; c < 512; c += 256) {
            int row = c >> 2, kc = (c & 3) * 8;
            *(u16x8*)&As[row * 40 + kc] =
                *(const u16x8*)(A1 + (size_t)(n0 + row) * CH + k0 + kc);
            *(u16x8*)&Xs[row * 40 + kc] =
                *(const u16x8*)(Xg + (size_t)row * CH + k0 + kc);
        }
        __syncthreads();
        short8 af[4], bfr[4];
        #pragma unroll
        for (int i = 0; i < 4; ++i)
            af[i] = *(const short8*)&As[(wn + i * 16 + l15) * 40 + quad * 8];
        #pragma unroll
        for (int j = 0; j < 4; ++j)
            bfr[j] = *(const short8*)&Xs[(wm + j * 16 + l15) * 40 + quad * 8];
        #pragma unroll
        for (int i = 0; i < 4; ++i)
            #pragma unroll
            for (int j = 0; j < 4; ++j)
                acc[i][j] = __builtin_amdgcn_mfma_f32_16x16x32_bf16(
                    af[i], bfr[j], acc[i][j], 0, 0, 0);
        __syncthreads();
    }

    if (n0 < 256) {
        #pragma unroll
        for (int i = 0; i < 4; ++i) {
            int nb = n0 + wn + i * 16 + quad * 4;
            #pragma unroll
            for (int r = 0; r < 4; ++r) {
                int n = nb + r;
                #pragma unroll
                for (int j = 0; j < 4; ++j) {
                    int m = m0 + wm + j * 16 + l15;
                    T[((size_t)b * CH + n) * HW0 + m] = acc[i][j][r];
                }
            }
        }
    } else {
        // LDS transpose: 4 passes over 32-pixel m-quarters.
        // tf[32][132] f32 (16.9 KB, aliases GEMM smem).
        float* tf = (float*)smem;
        const int nc = n0 - 256;
        #pragma unroll
        for (int mq = 0; mq < 4; ++mq) {
            __syncthreads();
            if ((wid & 1) == (mq >> 1)) {
                #pragma unroll
                for (int jj = 0; jj < 2; ++jj) {
                    int j = (mq & 1) * 2 + jj;
                    int ml = j * 16 + l15 - (mq & 1) * 32;   // 0..31
                    #pragma unroll
                    for (int i = 0; i < 4; ++i) {
                        int nl = wn + i * 16 + quad * 4;
                        #pragma unroll
                        for (int r = 0; r < 4; ++r)
                            tf[ml * 132 + nl + r] = acc[i][j][r] + bfv[nc + nl + r];
                    }
                }
            }
            __syncthreads();
            int mm = tid >> 3;            // 0..31
            int c8 = tid & 7;
            float* dst = procT + ((size_t)b * HW0 + m0 + mq * 32 + mm) * CH + nc;
            #pragma unroll
            for (int k = 0; k < 4; ++k) {
                int col = c8 * 4 + k * 32;
                *(float4*)(dst + col) = *(const float4*)&tf[mm * 132 + col];
            }
        }
    }
}

// ---------------------------------------------------------------------------
// K2: MFMA GEMM + fused upsample epilogue:
//   val[n, y, x] = relu( A2[n,:].lowT[m,:] + up2x(T)[n,y,x] + b1[n] )
// Written TRANSPOSED as off_featT[b][pix][256] bf16 via LDS transpose
// (k-contiguous layout for K3's MFMA conv).
// Block covers one output row y (m0 = y*128).  Grid (128, 2, B).
// ---------------------------------------------------------------------------
__global__ __launch_bounds__(256) void k2_mfma(
    const unsigned short* __restrict__ lowT,   // [B][16384][256]
    const unsigned short* __restrict__ A2,     // [256][256]
    const float* __restrict__ b1, const float* __restrict__ T,
    unsigned short* __restrict__ off_featT)
{
    const int b = blockIdx.z;
    const int m0 = blockIdx.x * 128;   // over 16384; y = blockIdx.x
    const int n0 = blockIdx.y * 128;   // over 256
    const int tid = threadIdx.x;
    __shared__ unsigned short smem[2 * 128 * 40];
    unsigned short* As = smem;
    unsigned short* Xs = smem + 128 * 40;
    const int lane = tid & 63, wid = tid >> 6;
    const int wn = (wid >> 1) * 64, wm = (wid & 1) * 64;
    const int l15 = lane & 15, quad = lane >> 4;

    floatx4 acc[4][4];
    #pragma unroll
    for (int i = 0; i < 4; ++i)
        #pragma unroll
        for (int j = 0; j < 4; ++j)
            acc[i][j] = (floatx4){0.f, 0.f, 0.f, 0.f};

    const unsigned short* Xg = lowT + ((size_t)b * HW2 + m0) * CH;

    for (int k0 = 0; k0 < 256; k0 += 32) {
        for (int c = tid; c < 512; c += 256) {
            int row = c >> 2, kc = (c & 3) * 8;
            *(u16x8*)&As[row * 40 + kc] =
                *(const u16x8*)(A2 + (size_t)(n0 + row) * CH + k0 + kc);
            *(u16x8*)&Xs[row * 40 + kc] =
                *(const u16x8*)(Xg + (size_t)row * CH + k0 + kc);
        }
        __syncthreads();
        short8 af[4], bfr[4];
        #pragma unroll
        for (int i = 0; i < 4; ++i)
            af[i] = *(const short8*)&As[(wn + i * 16 + l15) * 40 + quad * 8];
        #pragma unroll
        for (int j = 0; j < 4; ++j)
            bfr[j] = *(const short8*)&Xs[(wm + j * 16 + l15) * 40 + quad * 8];
        #pragma unroll
        for (int i = 0; i < 4; ++i)
            #pragma unroll
            for (int j = 0; j < 4; ++j)
                acc[i][j] = __builtin_amdgcn_mfma_f32_16x16x32_bf16(
                    af[i], bfr[j], acc[i][j], 0, 0, 0);
        __syncthreads();
    }

    // epilogue: upsample taps. y uniform per block.
    const int y = blockIdx.x;
    int hk = y >> 1;
    int yA, yB; float wyA, wyB;
    if (y & 1) { yA = hk; yB = min(hk + 1, 63); wyA = 0.75f; wyB = 0.25f; }
    else       { yB = hk; yA = max(hk - 1, 0);  wyA = 0.25f; wyB = 0.75f; }

    int xA[4], xB[4]; float wxA[4], wxB[4];
    #pragma unroll
    for (int j = 0; j < 4; ++j) {
        int x = wm + j * 16 + l15;
        int xk = x >> 1;
        if (x & 1) { xA[j] = xk; xB[j] = min(xk + 1, 63); wxA[j] = 0.75f; wxB[j] = 0.25f; }
        else       { xB[j] = xk; xA[j] = max(xk - 1, 0);  wxA[j] = 0.25f; wxB[j] = 0.75f; }
    }

    // compute final (relu'd) values in place
    #pragma unroll
    for (int i = 0; i < 4; ++i) {
        int nb = n0 + wn + i * 16 + quad * 4;
        #pragma unroll
        for (int r = 0; r < 4; ++r) {
            int n = nb + r;
            const float* tb  = T + ((size_t)b * CH + n) * HW0;
            const float* trA = tb + yA * 64;
            const float* trB = tb + yB * 64;
            float bias = b1[n];
            #pragma unroll
            for (int j = 0; j < 4; ++j) {
                float up = wyA * (wxA[j] * trA[xA[j]] + wxB[j] * trA[xB[j]])
                         + wyB * (wxA[j] * trB[xA[j]] + wxB[j] * trB[xB[j]]);
                acc[i][j][r] = fmaxf(acc[i][j][r] + up + bias, 0.0f);
            }
        }
    }

    // LDS transpose: two passes of [64 x][128 n], write k-contiguous bf16.
    unsigned short (*tile)[136] = (unsigned short (*)[136])smem;
    for (int xh = 0; xh < 2; ++xh) {
        __syncthreads();
        if ((wid & 1) == xh) {
            #pragma unroll
            for (int i = 0; i < 4; ++i) {
                int nc = wn + i * 16 + quad * 4;
                #pragma unroll
                for (int j = 0; j < 4; ++j) {
                    int xr = j * 16 + l15;
                    unsigned int lo = (unsigned int)f2bf(acc[i][j][0])
                                    | ((unsigned int)f2bf(acc[i][j][1]) << 16);
                    unsigned int hi = (unsigned int)f2bf(acc[i][j][2])
                                    | ((unsigned int)f2bf(acc[i][j][3]) << 16);
                    *(unsigned int*)&tile[xr][nc]     = lo;
                    *(unsigned int*)&tile[xr][nc + 2] = hi;
                }
            }
        }
        __syncthreads();
        for (int c = tid; c < 1024; c += 256) {
            int xr = c >> 4, nc = (c & 15) * 8;
            u16x8 v = *(u16x8*)&tile[xr][nc];
            *(u16x8*)(off_featT +
                ((size_t)b * HW2 + (size_t)y * 128 + xh * 64 + xr) * CH + n0 + nc) = v;
        }
    }
}

// ---------------------------------------------------------------------------
// K3: offsets = conv3x3(off_featT, W3p) via MFMA.
// Block = one row y (128 px), all 8 out channels (padded to 16), full K=2304.
// 4 waves x 32 px each. A-frag = pixels (k-contig off_featT), B-frag = W3p.
// No split-K, no atomics, no memset.
// ---------------------------------------------------------------------------
__global__ __launch_bounds__(256) void k3_mfma(
    const unsigned short* __restrict__ offT,   // [B][16384][256] bf16
    const unsigned short* __restrict__ W3p,    // [9][16][256] bf16
    float* __restrict__ offs)
{
    const int b = blockIdx.y;
    const int y = blockIdx.x;          // 0..127
    const int tid = threadIdx.x;
    const int lane = tid & 63, w = tid >> 6;
    const int l15 = lane & 15, quad = lane >> 4;

    floatx4 acc[2];
    acc[0] = (floatx4){0.f, 0.f, 0.f, 0.f};
    acc[1] = (floatx4){0.f, 0.f, 0.f, 0.f};

    const unsigned short* xb = offT + (size_t)b * HW2 * CH;
    const int xbase = w * 32 + l15;

    for (int k0 = 0; k0 < 256; k0 += 32) {
        #pragma unroll
        for (int t = 0; t < 9; ++t) {
            const int dy = t / 3 - 1, dx = t % 3 - 1;
            const int yy = y + dy;
            if ((unsigned)yy >= 128u) continue;   // uniform: zero-pad row
            short8 bw = *(const short8*)(W3p + (size_t)(t * 16 + l15) * CH
                                         + k0 + quad * 8);
            const unsigned short* rowp = xb + ((size_t)yy * 128) * CH + k0 + quad * 8;
            #pragma unroll
            for (int j = 0; j < 2; ++j) {
                int xx = xbase + j * 16 + dx;
                short8 ax = (short8){0, 0, 0, 0, 0, 0, 0, 0};
                if ((unsigned)xx < 128u)
                    ax = *(const short8*)(rowp + (size_t)xx * CH);
                acc[j] = __builtin_amdgcn_mfma_f32_16x16x32_bf16(
                    ax, bw, acc[j], 0, 0, 0);
            }
        }
    }

    // D: col(l15)=out channel, row(quad*4+r)=pixel within fragment
    if (l15 < 8) {
        float* ob = offs + ((size_t)b * 8 + l15) * HW2 + (size_t)y * 128;
        #pragma unroll
        for (int j = 0; j < 2; ++j) {
            int xpix = w * 32 + j * 16 + quad * 4;
            *(floatx4*)(ob + xpix) = acc[j];
        }
    }
}

// ---------------------------------------------------------------------------
// K4: deformable 4-point border-clamped bilinear sample of procT, averaged.
// Lanes = channels (coalesced 256B tap loads from procT[b][pix][256]);
// per-pixel params broadcast from LDS; NCHW output restored via wave-private
// 16x65 LDS transpose.  Grid: flat 2048 blocks, b = blk&7 (XCD affinity:
// 8 batches == 8 XCDs, proc[b] 4MB fits one XCD L2).
// ---------------------------------------------------------------------------
__global__ __launch_bounds__(256) void k4_sample(
    const float* __restrict__ offs, const float* __restrict__ b2v,
    const float* __restrict__ procT, float* __restrict__ out)
{
    const int blk = blockIdx.x;
    const int b  = blk & 7;
    const int r  = blk >> 3;       // 0..255
    const int y  = r >> 1;
    const int xt = r & 1;
    const int tid = threadIdx.x;
    const int lane = tid & 63, w = tid >> 6;

    __shared__ float4 sp[4][64];               // per-pixel: idx, pack(dx,dy), fx, fy
    __shared__ float tile[4][16 * 65];         // wave-private transpose buffers

    if (tid < 64) {
        int x = xt * 64 + tid;
        float gxb = (2.0f * x) / 127.0f - 1.0f;
        float gyb = (2.0f * y) / 127.0f - 1.0f;
        const float* ob = offs + (size_t)b * 8 * HW2 + y * 128 + x;
        #pragma unroll
        for (int p = 0; p < 4; ++p) {
            float ox = ob[(2 * p) * HW2] + b2v[2 * p];
            float oy = ob[(2 * p + 1) * HW2] + b2v[2 * p + 1];
            float gx = gxb + ox * (2.0f / 128.0f);
            float gy = gyb + oy * (2.0f / 128.0f);
            float gxp = fminf(fmaxf((gx + 1.0f) * 32.0f - 0.5f, 0.0f), 63.0f);
            float gyp = fminf(fmaxf((gy + 1.0f) * 32.0f - 0.5f, 0.0f), 63.0f);
            float x0f = floorf(gxp), y0f = floorf(gyp);
            int x0 = (int)x0f, y0 = (int)y0f;
            int idx = (y0 * 64 + x0) * 256;          // float offset into procT[b]
            int dxo = (x0 < 63) ? 256 : 0;           // +1 px in x
            int dyo = (y0 < 63) ? 16384 : 0;         // +1 px in y (64*256)
            sp[p][tid] = make_float4(__int_as_float(idx),
                                     __int_as_float(dxo | (dyo << 16)),
                                     gxp - x0f, gyp - y0f);
        }
    }
    __syncthreads();

    const float* P = procT + (size_t)b * HW0 * CH + w * 64 + lane;
    float* tw = &tile[w][0];
    float* outb = out + ((size_t)b * CH + w * 64) * HW2 + (size_t)y * 128 + xt * 64;

    for (int chunk = 0; chunk < 4; ++chunk) {
        float a[16];
        #pragma unroll
        for (int i = 0; i < 16; ++i) a[i] = 0.f;
        #pragma unroll
        for (int i = 0; i < 16; ++i) {
            int px = chunk * 16 + i;
            #pragma unroll
            for (int p = 0; p < 4; ++p) {
                float4 s = sp[p][px];                  // broadcast ds_read_b128
                int idx  = __float_as_int(s.x);
                int pack = __float_as_int(s.y);
                int dxo = pack & 0xFFFF, dyo = pack >> 16;
                const float* q = P + idx;
                float v00 = q[0];
                float v01 = q[dxo];
                float v10 = q[dyo];
                float v11 = q[dyo + dxo];
                float top = v00 + s.z * (v01 - v00);
                float bot = v10 + s.z * (v11 - v10);
                a[i] += top + s.w * (bot - top);
            }
        }
        // wave-private transpose: tw[px][c] then write NCHW rows coalesced
        #pragma unroll
        for (int i = 0; i < 16; ++i) tw[i * 65 + lane] = a[i] * 0.25f;
        #pragma unroll
        for (int g = 0; g < 16; ++g) {
            int c   = g * 4 + (lane >> 4);
            int pxl = lane & 15;
            outb[(size_t)c * HW2 + chunk * 16 + pxl] = tw[pxl * 65 + c];
        }
    }
}

// ---------------------------------------------------------------------------
extern "C" void kernel_launch(void* const* d_in, const int* in_sizes, int n_in,
                              void* d_out, int out_size, void* d_ws, size_t ws_size,
                              hipStream_t stream) {
    const float* high = (const float*)d_in[0];
    const float* low  = (const float*)d_in[1];
    const float* W1   = (const float*)d_in[2];
    const float* b1   = (const float*)d_in[3];
    const float* W2v  = (const float*)d_in[4];
    const float* b2v  = (const float*)d_in[5];
    const float* Wf   = (const float*)d_in[6];
    const float* bfv  = (const float*)d_in[7];
    float* out = (float*)d_out;
    float* ws  = (float*)d_ws;

    // ws layout (floats):
    float* T     = ws;                       // 8*256*4096  = 8388608
    float* procT = ws + 8388608;             // 8388608  ([B][4096][256] now)
    float* offs  = ws + 16777216;            // 1048576
    unsigned short* highT = (unsigned short*)(ws + 17825792);  // 8388608 shorts
    unsigned short* A1 = highT + 8388608;   // 131072 shorts
    unsigned short* A2 = A1 + 131072;       // 65536 shorts  (total ~88.5 MB)

    // W3p reuses highT's storage — written only AFTER k1 (highT dead by then).
    unsigned short* W3p = highT;            // 36864 shorts

    // d_out (33554432 floats = 134 MB) doubles as scratch:
    unsigned short* lowT      = (unsigned short*)out;              // 33554432 shorts
    unsigned short* off_featT = ((unsigned short*)out) + 33554432; // 33554432 shorts

    // transpose+convert inputs to bf16 [b][m][k]
    ktrans<<<dim3(32, 8, NB), 256, 0, stream>>>(high, highT, HW0);
    ktrans<<<dim3(128, 8, NB), 256, 0, stream>>>(low, lowT, HW2);
    kwconv<<<dim3(512), 256, 0, stream>>>(W1, Wf, A1, A2);

    // T = W1a@high (row-major), procT = (Wf@high + bf) transposed  (bf16 MFMA)
    k1_mfma<<<dim3(32, 4, NB), 256, 0, stream>>>(highT, A1, bfv, T, procT);
    // pack conv3x3 weights (over dead highT region)
    kwpack<<<dim3(144), 256, 0, stream>>>(W2v, W3p);
    // off_featT = relu(W1b@low + up2x(T) + b1)  -> bf16 [b][pix][256]
    k2_mfma<<<dim3(128, 2, NB), 256, 0, stream>>>(lowT, A2, b1, T, off_featT);
    // offs = conv3x3(off_featT, W2)  (MFMA, full-K per block, no atomics)
    k3_mfma<<<dim3(128, NB), 256, 0, stream>>>(off_featT, W3p, offs);
    // out = mean over 4 deformable bilinear samples of procT (coalesced gather)
    k4_sample<<<dim3(2048), 256, 0, stream>>>(offs, b2v, procT, out);
}

// Round 4
// 540.194 us; speedup vs baseline: 1.2599x; 1.0200x over previous
//
#include <hip/hip_runtime.h>
#include <stdint.h>

// Problem constants: B=8, Cin=Cout=256, H=W=64, H2=W2=128, P=4 points.
#define NB   8
#define CH   256
#define HW0  4096    // 64*64
#define HW2  16384   // 128*128

typedef __attribute__((ext_vector_type(8))) short short8;
typedef __attribute__((ext_vector_type(8))) unsigned short u16x8;
typedef __attribute__((ext_vector_type(4))) unsigned short u16x4;
typedef __attribute__((ext_vector_type(4))) float floatx4;

__device__ inline unsigned short f2bf(float f) {
    union { float f; uint32_t u; } v; v.f = f;
    return (unsigned short)((v.u + 0x7FFFu + ((v.u >> 16) & 1u)) >> 16);
}
__device__ inline float bf2f(unsigned short h) {
    union { uint32_t u; float f; } v; v.u = ((uint32_t)h) << 16;
    return v.f;
}

// ---------------------------------------------------------------------------
// ktrans: [B][256][M] f32  ->  [B][M][256] bf16   (transpose + convert)
// ---------------------------------------------------------------------------
__global__ __launch_bounds__(256) void ktrans(const float* __restrict__ src,
        unsigned short* __restrict__ dst, int M) {
    const int b = blockIdx.z, k0 = blockIdx.y * 32, m0 = blockIdx.x * 128;
    const int tid = threadIdx.x;
    __shared__ unsigned short tile[32][132];
    const float* s = src + ((size_t)b * CH + k0) * M + m0;
    for (int c = tid; c < 1024; c += 256) {
        int kk = c >> 5, mm = (c & 31) * 4;
        float4 v = *(const float4*)(s + (size_t)kk * M + mm);
        u16x4 o = { f2bf(v.x), f2bf(v.y), f2bf(v.z), f2bf(v.w) };
        *(u16x4*)&tile[kk][mm] = o;
    }
    __syncthreads();
    unsigned short* d = dst + ((size_t)b * M + m0) * CH + k0;
    for (int c = tid; c < 512; c += 256) {
        int mm = c >> 2, kc = (c & 3) * 8;
        u16x8 v;
        #pragma unroll
        for (int i = 0; i < 8; ++i) v[i] = tile[kc + i][mm];
        *(u16x8*)(d + (size_t)mm * CH + kc) = v;
    }
}

// ---------------------------------------------------------------------------
// kwconv: pack weights to bf16.  A1[512][256]: rows 0-255 = W1a, 256-511 = Wf.
// A2[256][256] = W1b.
// ---------------------------------------------------------------------------
__global__ __launch_bounds__(256) void kwconv(const float* __restrict__ W1,
        const float* __restrict__ Wf, unsigned short* __restrict__ A1,
        unsigned short* __restrict__ A2) {
    int i = blockIdx.x * 256 + threadIdx.x;
    if (i < 512 * 256) {
        int n = i >> 8, k = i & 255;
        float v = (n < 256) ? W1[n * 512 + k] : Wf[(size_t)(n - 256) * 256 + k];
        A1[i] = f2bf(v);
    }
    if (i < 256 * 256) {
        int n = i >> 8, k = i & 255;
        A2[i] = f2bf(W1[n * 512 + 256 + k]);
    }
}

// ---------------------------------------------------------------------------
// kwpack: W2 [8][256][3][3] f32 -> W3p [9 taps][16 o (8 padded)][256 ci] bf16
// Launched AFTER k1 (reuses the then-dead highT buffer).
// ---------------------------------------------------------------------------
__global__ __launch_bounds__(256) void kwpack(const float* __restrict__ W2v,
        unsigned short* __restrict__ W3p) {
    int i = blockIdx.x * 256 + threadIdx.x;   // 9*16*256 = 36864
    if (i >= 9 * 16 * 256) return;
    int ci = i & 255, o = (i >> 8) & 15, t = i >> 12;
    float v = (o < 8) ? W2v[((size_t)o * 256 + ci) * 9 + t] : 0.0f;
    W3p[i] = f2bf(v);
}

// ---------------------------------------------------------------------------
// K1: dual MFMA GEMM:  D[n,m] = A1[n,:] . highT[m,:]   (k-contig both sides)
//   n<256 -> T[b][n][m]  (row-major, consumed by K2's upsample taps)
//   n>=256 -> procT[b][m][n-256] + bf   (TRANSPOSED via LDS; channel-contig
//             layout consumed by K4's coalesced gather)
// Tile 128(n) x 128(m), 4 waves of 64x64, 16x16x32 bf16 MFMA.
// ---------------------------------------------------------------------------
__global__ __launch_bounds__(256) void k1_mfma(
    const unsigned short* __restrict__ highT,  // [B][4096][256]
    const unsigned short* __restrict__ A1,     // [512][256]
    const float* __restrict__ bfv,
    float* __restrict__ T, float* __restrict__ procT)
{
    const int b = blockIdx.z;
    const int m0 = blockIdx.x * 128;   // over 4096
    const int n0 = blockIdx.y * 128;   // over 512
    const int tid = threadIdx.x;
    __shared__ __attribute__((aligned(16))) unsigned short smem[2 * 128 * 40];
    unsigned short* As = smem;
    unsigned short* Xs = smem + 128 * 40;
    const int lane = tid & 63, wid = tid >> 6;
    const int wn = (wid >> 1) * 64, wm = (wid & 1) * 64;
    const int l15 = lane & 15, quad = lane >> 4;

    floatx4 acc[4][4];
    #pragma unroll
    for (int i = 0; i < 4; ++i)
        #pragma unroll
        for (int j = 0; j < 4; ++j)
            acc[i][j] = (floatx4){0.f, 0.f, 0.f, 0.f};

    const unsigned short* Xg = highT + ((size_t)b * HW0 + m0) * CH;

    for (int k0 = 0; k0 < 256; k0 += 32) {
        for (int c = tid; c < 512; c += 256) {
            int row = c >> 2, kc = (c & 3) * 8;
            *(u16x8*)&As[row * 40 + kc] =
                *(const u16x8*)(A1 + (size_t)(n0 + row) * CH + k0 + kc);
            *(u16x8*)&Xs[row * 40 + kc] =
                *(const u16x8*)(Xg + (size_t)row * CH + k0 + kc);
        }
        __syncthreads();
        short8 af[4], bfr[4];
        #pragma unroll
        for (int i = 0; i < 4; ++i)
            af[i] = *(const short8*)&As[(wn + i * 16 + l15) * 40 + quad * 8];
        #pragma unroll
        for (int j = 0; j < 4; ++j)
            bfr[j] = *(const short8*)&Xs[(wm + j * 16 + l15) * 40 + quad * 8];
        #pragma unroll
        for (int i = 0; i < 4; ++i)
            #pragma unroll
            for (int j = 0; j < 4; ++j)
                acc[i][j] = __builtin_amdgcn_mfma_f32_16x16x32_bf16(
                    af[i], bfr[j], acc[i][j], 0, 0, 0);
        __syncthreads();
    }

    if (n0 < 256) {
        #pragma unroll
        for (int i = 0; i < 4; ++i) {
            int nb = n0 + wn + i * 16 + quad * 4;
            #pragma unroll
            for (int r = 0; r < 4; ++r) {
                int n = nb + r;
                #pragma unroll
                for (int j = 0; j < 4; ++j) {
                    int m = m0 + wm + j * 16 + l15;
                    T[((size_t)b * CH + n) * HW0 + m] = acc[i][j][r];
                }
            }
        }
    } else {
        // LDS transpose: 4 passes over 32-pixel m-quarters.
        // tf[32][132] f32 (16.9 KB, aliases GEMM smem).
        float* tf = (float*)smem;
        const int nc = n0 - 256;
        #pragma unroll
        for (int mq = 0; mq < 4; ++mq) {
            __syncthreads();
            if ((wid & 1) == (mq >> 1)) {
                #pragma unroll
                for (int jj = 0; jj < 2; ++jj) {
                    int j = (mq & 1) * 2 + jj;
                    int ml = j * 16 + l15 - (mq & 1) * 32;   // 0..31
                    #pragma unroll
                    for (int i = 0; i < 4; ++i) {
                        int nl = wn + i * 16 + quad * 4;
                        #pragma unroll
                        for (int r = 0; r < 4; ++r)
                            tf[ml * 132 + nl + r] = acc[i][j][r] + bfv[nc + nl + r];
                    }
                }
            }
            __syncthreads();
            int mm = tid >> 3;            // 0..31
            int c8 = tid & 7;
            float* dst = procT + ((size_t)b * HW0 + m0 + mq * 32 + mm) * CH + nc;
            #pragma unroll
            for (int k = 0; k < 4; ++k) {
                int col = c8 * 4 + k * 32;
                *(float4*)(dst + col) = *(const float4*)&tf[mm * 132 + col];
            }
        }
    }
}

// ---------------------------------------------------------------------------
// K2: MFMA GEMM + fused upsample epilogue:
//   val[n, y, x] = relu( A2[n,:].lowT[m,:] + up2x(T)[n,y,x] + b1[n] )
// Written TRANSPOSED as off_featT[b][pix][256] bf16 via LDS transpose
// (k-contiguous layout for K3's MFMA conv).
// Block covers one output row y (m0 = y*128).  Grid (128, 2, B).
// ---------------------------------------------------------------------------
__global__ __launch_bounds__(256) void k2_mfma(
    const unsigned short* __restrict__ lowT,   // [B][16384][256]
    const unsigned short* __restrict__ A2,     // [256][256]
    const float* __restrict__ b1, const float* __restrict__ T,
    unsigned short* __restrict__ off_featT)
{
    const int b = blockIdx.z;
    const int m0 = blockIdx.x * 128;   // over 16384; y = blockIdx.x
    const int n0 = blockIdx.y * 128;   // over 256
    const int tid = threadIdx.x;
    __shared__ unsigned short smem[2 * 128 * 40];
    unsigned short* As = smem;
    unsigned short* Xs = smem + 128 * 40;
    const int lane = tid & 63, wid = tid >> 6;
    const int wn = (wid >> 1) * 64, wm = (wid & 1) * 64;
    const int l15 = lane & 15, quad = lane >> 4;

    floatx4 acc[4][4];
    #pragma unroll
    for (int i = 0; i < 4; ++i)
        #pragma unroll
        for (int j = 0; j < 4; ++j)
            acc[i][j] = (floatx4){0.f, 0.f, 0.f, 0.f};

    const unsigned short* Xg = lowT + ((size_t)b * HW2 + m0) * CH;

    for (int k0 = 0; k0 < 256; k0 += 32) {
        for (int c = tid; c < 512; c += 256) {
            int row = c >> 2, kc = (c & 3) * 8;
            *(u16x8*)&As[row * 40 + kc] =
                *(const u16x8*)(A2 + (size_t)(n0 + row) * CH + k0 + kc);
            *(u16x8*)&Xs[row * 40 + kc] =
                *(const u16x8*)(Xg + (size_t)row * CH + k0 + kc);
        }
        __syncthreads();
        short8 af[4], bfr[4];
        #pragma unroll
        for (int i = 0; i < 4; ++i)
            af[i] = *(const short8*)&As[(wn + i * 16 + l15) * 40 + quad * 8];
        #pragma unroll
        for (int j = 0; j < 4; ++j)
            bfr[j] = *(const short8*)&Xs[(wm + j * 16 + l15) * 40 + quad * 8];
        #pragma unroll
        for (int i = 0; i < 4; ++i)
            #pragma unroll
            for (int j = 0; j < 4; ++j)
                acc[i][j] = __builtin_amdgcn_mfma_f32_16x16x32_bf16(
                    af[i], bfr[j], acc[i][j], 0, 0, 0);
        __syncthreads();
    }

    // epilogue: upsample taps. y uniform per block.
    const int y = blockIdx.x;
    int hk = y >> 1;
    int yA, yB; float wyA, wyB;
    if (y & 1) { yA = hk; yB = min(hk + 1, 63); wyA = 0.75f; wyB = 0.25f; }
    else       { yB = hk; yA = max(hk - 1, 0);  wyA = 0.25f; wyB = 0.75f; }

    int xA[4], xB[4]; float wxA[4], wxB[4];
    #pragma unroll
    for (int j = 0; j < 4; ++j) {
        int x = wm + j * 16 + l15;
        int xk = x >> 1;
        if (x & 1) { xA[j] = xk; xB[j] = min(xk + 1, 63); wxA[j] = 0.75f; wxB[j] = 0.25f; }
        else       { xB[j] = xk; xA[j] = max(xk - 1, 0);  wxA[j] = 0.25f; wxB[j] = 0.75f; }
    }

    // compute final (relu'd) values in place
    #pragma unroll
    for (int i = 0; i < 4; ++i) {
        int nb = n0 + wn + i * 16 + quad * 4;
        #pragma unroll
        for (int r = 0; r < 4; ++r) {
            int n = nb + r;
            const float* tb  = T + ((size_t)b * CH + n) * HW0;
            const float* trA = tb + yA * 64;
            const float* trB = tb + yB * 64;
            float bias = b1[n];
            #pragma unroll
            for (int j = 0; j < 4; ++j) {
                float up = wyA * (wxA[j] * trA[xA[j]] + wxB[j] * trA[xB[j]])
                         + wyB * (wxA[j] * trB[xA[j]] + wxB[j] * trB[xB[j]]);
                acc[i][j][r] = fmaxf(acc[i][j][r] + up + bias, 0.0f);
            }
        }
    }

    // LDS transpose: two passes of [64 x][128 n], write k-contiguous bf16.
    unsigned short (*tile)[136] = (unsigned short (*)[136])smem;
    for (int xh = 0; xh < 2; ++xh) {
        __syncthreads();
        if ((wid & 1) == xh) {
            #pragma unroll
            for (int i = 0; i < 4; ++i) {
                int nc = wn + i * 16 + quad * 4;
                #pragma unroll
                for (int j = 0; j < 4; ++j) {
                    int xr = j * 16 + l15;
                    unsigned int lo = (unsigned int)f2bf(acc[i][j][0])
                                    | ((unsigned int)f2bf(acc[i][j][1]) << 16);
                    unsigned int hi = (unsigned int)f2bf(acc[i][j][2])
                                    | ((unsigned int)f2bf(acc[i][j][3]) << 16);
                    *(unsigned int*)&tile[xr][nc]     = lo;
                    *(unsigned int*)&tile[xr][nc + 2] = hi;
                }
            }
        }
        __syncthreads();
        for (int c = tid; c < 1024; c += 256) {
            int xr = c >> 4, nc = (c & 15) * 8;
            u16x8 v = *(u16x8*)&tile[xr][nc];
            *(u16x8*)(off_featT +
                ((size_t)b * HW2 + (size_t)y * 128 + xh * 64 + xr) * CH + n0 + nc) = v;
        }
    }
}

// ---------------------------------------------------------------------------
// K3: offsets = conv3x3(off_featT, W3p) via MFMA.
// Block = one row y (128 px), all 8 out channels (padded to 16), full K=2304.
// 4 waves x 32 px each. A-frag = pixels (k-contig off_featT), B-frag = W3p.
// No split-K, no atomics, no memset.
// ---------------------------------------------------------------------------
__global__ __launch_bounds__(256) void k3_mfma(
    const unsigned short* __restrict__ offT,   // [B][16384][256] bf16
    const unsigned short* __restrict__ W3p,    // [9][16][256] bf16
    float* __restrict__ offs)
{
    const int b = blockIdx.y;
    const int y = blockIdx.x;          // 0..127
    const int tid = threadIdx.x;
    const int lane = tid & 63, w = tid >> 6;
    const int l15 = lane & 15, quad = lane >> 4;

    floatx4 acc[2];
    acc[0] = (floatx4){0.f, 0.f, 0.f, 0.f};
    acc[1] = (floatx4){0.f, 0.f, 0.f, 0.f};

    const unsigned short* xb = offT + (size_t)b * HW2 * CH;
    const int xbase = w * 32 + l15;

    for (int k0 = 0; k0 < 256; k0 += 32) {
        #pragma unroll
        for (int t = 0; t < 9; ++t) {
            const int dy = t / 3 - 1, dx = t % 3 - 1;
            const int yy = y + dy;
            if ((unsigned)yy >= 128u) continue;   // uniform: zero-pad row
            short8 bw = *(const short8*)(W3p + (size_t)(t * 16 + l15) * CH
                                         + k0 + quad * 8);
            const unsigned short* rowp = xb + ((size_t)yy * 128) * CH + k0 + quad * 8;
            #pragma unroll
            for (int j = 0; j < 2; ++j) {
                int xx = xbase + j * 16 + dx;
                short8 ax = (short8){0, 0, 0, 0, 0, 0, 0, 0};
                if ((unsigned)xx < 128u)
                    ax = *(const short8*)(rowp + (size_t)xx * CH);
                acc[j] = __builtin_amdgcn_mfma_f32_16x16x32_bf16(
                    ax, bw, acc[j], 0, 0, 0);
            }
        }
    }

    // D: col(l15)=out channel, row(quad*4+r)=pixel within fragment
    if (l15 < 8) {
        float* ob = offs + ((size_t)b * 8 + l15) * HW2 + (size_t)y * 128;
        #pragma unroll
        for (int j = 0; j < 2; ++j) {
            int xpix = w * 32 + j * 16 + quad * 4;
            *(floatx4*)(ob + xpix) = acc[j];
        }
    }
}

// ---------------------------------------------------------------------------
// K4: deformable 4-point border-clamped bilinear sample of procT, averaged.
// Each lane loads float4 (4 channels) -> one wave covers all 256 ch per tap
// (1024B coalesced wave-loads, 4x fewer VMEM instrs than 1-ch/lane).
// Per-(px,pt) bilinear weights (pre-scaled by 0.25) + packed idx/dxo/dyo
// precomputed in LDS.  Wave owns 16 px; NCHW restored via per-wave [8][260]
// LDS transpose tiles.  Grid: flat 2048 blocks, b = blk&7 (XCD affinity).
// ---------------------------------------------------------------------------
__global__ __launch_bounds__(256) void k4_sample(
    const float* __restrict__ offs, const float* __restrict__ b2v,
    const float* __restrict__ procT, float* __restrict__ out)
{
    const int blk = blockIdx.x;
    const int b  = blk & 7;
    const int r  = blk >> 3;       // 0..255
    const int y  = r >> 1;
    const int xh = r & 1;          // 64-px half row
    const int tid = threadIdx.x;
    const int lane = tid & 63, w = tid >> 6;

    __shared__ int2   sp_i[4][64];     // [p][px]: gather idx, pack(dxo,dyo)
    __shared__ float4 sp_w[4][64];     // [p][px]: 0.25*bilinear weights
    __shared__ float  tile[4][8 * 260];

    if (tid < 64) {
        int x = xh * 64 + tid;
        float gxb = (2.0f * x) / 127.0f - 1.0f;
        float gyb = (2.0f * y) / 127.0f - 1.0f;
        const float* ob = offs + (size_t)b * 8 * HW2 + y * 128 + x;
        #pragma unroll
        for (int p = 0; p < 4; ++p) {
            float ox = ob[(2 * p) * HW2] + b2v[2 * p];
            float oy = ob[(2 * p + 1) * HW2] + b2v[2 * p + 1];
            float gx = gxb + ox * (2.0f / 128.0f);
            float gy = gyb + oy * (2.0f / 128.0f);
            float gxp = fminf(fmaxf((gx + 1.0f) * 32.0f - 0.5f, 0.0f), 63.0f);
            float gyp = fminf(fmaxf((gy + 1.0f) * 32.0f - 0.5f, 0.0f), 63.0f);
            float x0f = floorf(gxp), y0f = floorf(gyp);
            int x0 = (int)x0f, y0 = (int)y0f;
            int idx = (y0 * 64 + x0) * 256;          // float offset into procT[b]
            int dxo = (x0 < 63) ? 256 : 0;           // +1 px in x
            int dyo = (y0 < 63) ? 16384 : 0;         // +1 px in y (64*256)
            float fx = gxp - x0f, fy = gyp - y0f;
            float ex = 1.0f - fx, ey = 1.0f - fy;
            sp_i[p][tid] = make_int2(idx, dxo | (dyo << 16));
            sp_w[p][tid] = make_float4(0.25f * ex * ey, 0.25f * fx * ey,
                                       0.25f * ex * fy, 0.25f * fx * fy);
        }
    }
    __syncthreads();

    const float* P = procT + (size_t)b * HW0 * CH + lane * 4;
    float* tw = &tile[w][0];
    float* outb = out + (size_t)b * CH * HW2 + (size_t)y * 128 + xh * 64 + w * 16;

    for (int c8 = 0; c8 < 2; ++c8) {
        #pragma unroll
        for (int i = 0; i < 8; ++i) {
            int lpx = w * 16 + c8 * 8 + i;     // local px, uniform per wave
            float4 a = make_float4(0.f, 0.f, 0.f, 0.f);
            #pragma unroll
            for (int p = 0; p < 4; ++p) {
                int2 si = sp_i[p][lpx];
                float4 sw = sp_w[p][lpx];
                int dxo = si.y & 0xFFFF, dyo = si.y >> 16;
                const float* q = P + si.x;
                float4 v00 = *(const float4*)(q);
                float4 v01 = *(const float4*)(q + dxo);
                float4 v10 = *(const float4*)(q + dyo);
                float4 v11 = *(const float4*)(q + dyo + dxo);
                a.x += sw.x * v00.x + sw.y * v01.x + sw.z * v10.x + sw.w * v11.x;
                a.y += sw.x * v00.y + sw.y * v01.y + sw.z * v10.y + sw.w * v11.y;
                a.z += sw.x * v00.z + sw.y * v01.z + sw.z * v10.z + sw.w * v11.z;
                a.w += sw.x * v00.w + sw.y * v01.w + sw.z * v10.w + sw.w * v11.w;
            }
            *(float4*)&tw[i * 260 + lane * 4] = a;
        }
        __syncthreads();
        // transposed write: 8 px x 256 ch, 32B segments, 2-way banks (free)
        #pragma unroll
        for (int g = 0; g < 32; ++g) {
            int c   = g * 8 + (lane >> 3);
            int pxl = lane & 7;
            outb[(size_t)c * HW2 + c8 * 8 + pxl] = tw[pxl * 260 + c];
        }
        __syncthreads();
    }
}

// ---------------------------------------------------------------------------
extern "C" void kernel_launch(void* const* d_in, const int* in_sizes, int n_in,
                              void* d_out, int out_size, void* d_ws, size_t ws_size,
                              hipStream_t stream) {
    const float* high = (const float*)d_in[0];
    const float* low  = (const float*)d_in[1];
    const float* W1   = (const float*)d_in[2];
    const float* b1   = (const float*)d_in[3];
    const float* W2v  = (const float*)d_in[4];
    const float* b2v  = (const float*)d_in[5];
    const float* Wf   = (const float*)d_in[6];
    const float* bfv  = (const float*)d_in[7];
    float* out = (float*)d_out;
    float* ws  = (float*)d_ws;

    // ws layout (floats):
    float* T     = ws;                       // 8*256*4096  = 8388608
    float* procT = ws + 8388608;             // 8388608  ([B][4096][256])
    float* offs  = ws + 16777216;            // 1048576
    unsigned short* highT = (unsigned short*)(ws + 17825792);  // 8388608 shorts
    unsigned short* A1 = highT + 8388608;   // 131072 shorts
    unsigned short* A2 = A1 + 131072;       // 65536 shorts  (total ~88.5 MB)

    // W3p reuses highT's storage — written only AFTER k1 (highT dead by then).
    unsigned short* W3p = highT;            // 36864 shorts

    // d_out (33554432 floats = 134 MB) doubles as scratch:
    unsigned short* lowT      = (unsigned short*)out;              // 33554432 shorts
    unsigned short* off_featT = ((unsigned short*)out) + 33554432; // 33554432 shorts

    // transpose+convert inputs to bf16 [b][m][k]
    ktrans<<<dim3(32, 8, NB), 256, 0, stream>>>(high, highT, HW0);
    ktrans<<<dim3(128, 8, NB), 256, 0, stream>>>(low, lowT, HW2);
    kwconv<<<dim3(512), 256, 0, stream>>>(W1, Wf, A1, A2);

    // T = W1a@high (row-major), procT = (Wf@high + bf) transposed  (bf16 MFMA)
    k1_mfma<<<dim3(32, 4, NB), 256, 0, stream>>>(highT, A1, bfv, T, procT);
    // pack conv3x3 weights (over dead highT region)
    kwpack<<<dim3(144), 256, 0, stream>>>(W2v, W3p);
    // off_featT = relu(W1b@low + up2x(T) + b1)  -> bf16 [b][pix][256]
    k2_mfma<<<dim3(128, 2, NB), 256, 0, stream>>>(lowT, A2, b1, T, off_featT);
    // offs = conv3x3(off_featT, W2)  (MFMA, full-K per block, no atomics)
    k3_mfma<<<dim3(128, NB), 256, 0, stream>>>(off_featT, W3p, offs);
    // out = mean over 4 deformable bilinear samples of procT (coalesced gather)
    k4_sample<<<dim3(2048), 256, 0, stream>>>(offs, b2v, procT, out);
}

// Round 5
// 512.044 us; speedup vs baseline: 1.3292x; 1.0550x over previous
//
#include <hip/hip_runtime.h>
#include <stdint.h>

// Problem constants: B=8, Cin=Cout=256, H=W=64, H2=W2=128, P=4 points.
#define NB   8
#define CH   256
#define HW0  4096    // 64*64
#define HW2  16384   // 128*128

typedef __attribute__((ext_vector_type(8))) short short8;
typedef __attribute__((ext_vector_type(8))) unsigned short u16x8;
typedef __attribute__((ext_vector_type(4))) unsigned short u16x4;
typedef __attribute__((ext_vector_type(4))) float floatx4;

__device__ inline unsigned short f2bf(float f) {
    union { float f; uint32_t u; } v; v.f = f;
    return (unsigned short)((v.u + 0x7FFFu + ((v.u >> 16) & 1u)) >> 16);
}
__device__ inline float bf2f(unsigned short h) {
    union { uint32_t u; float f; } v; v.u = ((uint32_t)h) << 16;
    return v.f;
}

// ---------------------------------------------------------------------------
// ktrans: [B][256][M] f32  ->  [B][M][256] bf16   (transpose + convert)
// Used only for high_feat now (low transpose fused into k2).
// ---------------------------------------------------------------------------
__global__ __launch_bounds__(256) void ktrans(const float* __restrict__ src,
        unsigned short* __restrict__ dst, int M) {
    const int b = blockIdx.z, k0 = blockIdx.y * 32, m0 = blockIdx.x * 128;
    const int tid = threadIdx.x;
    __shared__ unsigned short tile[32][132];
    const float* s = src + ((size_t)b * CH + k0) * M + m0;
    for (int c = tid; c < 1024; c += 256) {
        int kk = c >> 5, mm = (c & 31) * 4;
        float4 v = *(const float4*)(s + (size_t)kk * M + mm);
        u16x4 o = { f2bf(v.x), f2bf(v.y), f2bf(v.z), f2bf(v.w) };
        *(u16x4*)&tile[kk][mm] = o;
    }
    __syncthreads();
    unsigned short* d = dst + ((size_t)b * M + m0) * CH + k0;
    for (int c = tid; c < 512; c += 256) {
        int mm = c >> 2, kc = (c & 3) * 8;
        u16x8 v;
        #pragma unroll
        for (int i = 0; i < 8; ++i) v[i] = tile[kc + i][mm];
        *(u16x8*)(d + (size_t)mm * CH + kc) = v;
    }
}

// ---------------------------------------------------------------------------
// kwconv: pack weights to bf16.  A1[512][256]: rows 0-255 = W1a, 256-511 = Wf.
// A2[256][256] = W1b.
// ---------------------------------------------------------------------------
__global__ __launch_bounds__(256) void kwconv(const float* __restrict__ W1,
        const float* __restrict__ Wf, unsigned short* __restrict__ A1,
        unsigned short* __restrict__ A2) {
    int i = blockIdx.x * 256 + threadIdx.x;
    if (i < 512 * 256) {
        int n = i >> 8, k = i & 255;
        float v = (n < 256) ? W1[n * 512 + k] : Wf[(size_t)(n - 256) * 256 + k];
        A1[i] = f2bf(v);
    }
    if (i < 256 * 256) {
        int n = i >> 8, k = i & 255;
        A2[i] = f2bf(W1[n * 512 + 256 + k]);
    }
}

// ---------------------------------------------------------------------------
// kwpack: W2 [8][256][3][3] f32 -> W3p [9 taps][16 o (8 padded)][256 ci] bf16
// Launched AFTER k1 (reuses the then-dead highT buffer).
// ---------------------------------------------------------------------------
__global__ __launch_bounds__(256) void kwpack(const float* __restrict__ W2v,
        unsigned short* __restrict__ W3p) {
    int i = blockIdx.x * 256 + threadIdx.x;   // 9*16*256 = 36864
    if (i >= 9 * 16 * 256) return;
    int ci = i & 255, o = (i >> 8) & 15, t = i >> 12;
    float v = (o < 8) ? W2v[((size_t)o * 256 + ci) * 9 + t] : 0.0f;
    W3p[i] = f2bf(v);
}

// ---------------------------------------------------------------------------
// K1: dual MFMA GEMM:  D[n,m] = A1[n,:] . highT[m,:]   (k-contig both sides)
//   n<256 -> T[b][n][m]  (row-major, consumed by K2's upsample taps)
//   n>=256 -> procT[b][m][n-256] + bf   (TRANSPOSED via LDS; channel-contig
//             layout consumed by K4's coalesced gather)
// Flat grid 1024: b = bid&7 (XCD affinity: highT[b] = 2MB fits one XCD L2,
// so the 4 n-blocks re-reading the same X tile hit L2, not HBM).
// ---------------------------------------------------------------------------
__global__ __launch_bounds__(256) void k1_mfma(
    const unsigned short* __restrict__ highT,  // [B][4096][256]
    const unsigned short* __restrict__ A1,     // [512][256]
    const float* __restrict__ bfv,
    float* __restrict__ T, float* __restrict__ procT)
{
    const int bid = blockIdx.x;
    const int b  = bid & 7;
    const int q  = bid >> 3;            // 0..127
    const int m0 = (q & 31) * 128;      // over 4096
    const int n0 = (q >> 5) * 128;      // over 512
    const int tid = threadIdx.x;
    __shared__ __attribute__((aligned(16))) unsigned short smem[2 * 128 * 40];
    unsigned short* As = smem;
    unsigned short* Xs = smem + 128 * 40;
    const int lane = tid & 63, wid = tid >> 6;
    const int wn = (wid >> 1) * 64, wm = (wid & 1) * 64;
    const int l15 = lane & 15, quad = lane >> 4;

    floatx4 acc[4][4];
    #pragma unroll
    for (int i = 0; i < 4; ++i)
        #pragma unroll
        for (int j = 0; j < 4; ++j)
            acc[i][j] = (floatx4){0.f, 0.f, 0.f, 0.f};

    const unsigned short* Xg = highT + ((size_t)b * HW0 + m0) * CH;

    for (int k0 = 0; k0 < 256; k0 += 32) {
        for (int c = tid; c < 512; c += 256) {
            int row = c >> 2, kc = (c & 3) * 8;
            *(u16x8*)&As[row * 40 + kc] =
                *(const u16x8*)(A1 + (size_t)(n0 + row) * CH + k0 + kc);
            *(u16x8*)&Xs[row * 40 + kc] =
                *(const u16x8*)(Xg + (size_t)row * CH + k0 + kc);
        }
        __syncthreads();
        short8 af[4], bfr[4];
        #pragma unroll
        for (int i = 0; i < 4; ++i)
            af[i] = *(const short8*)&As[(wn + i * 16 + l15) * 40 + quad * 8];
        #pragma unroll
        for (int j = 0; j < 4; ++j)
            bfr[j] = *(const short8*)&Xs[(wm + j * 16 + l15) * 40 + quad * 8];
        #pragma unroll
        for (int i = 0; i < 4; ++i)
            #pragma unroll
            for (int j = 0; j < 4; ++j)
                acc[i][j] = __builtin_amdgcn_mfma_f32_16x16x32_bf16(
                    af[i], bfr[j], acc[i][j], 0, 0, 0);
        __syncthreads();
    }

    if (n0 < 256) {
        #pragma unroll
        for (int i = 0; i < 4; ++i) {
            int nb = n0 + wn + i * 16 + quad * 4;
            #pragma unroll
            for (int r = 0; r < 4; ++r) {
                int n = nb + r;
                #pragma unroll
                for (int j = 0; j < 4; ++j) {
                    int m = m0 + wm + j * 16 + l15;
                    T[((size_t)b * CH + n) * HW0 + m] = acc[i][j][r];
                }
            }
        }
    } else {
        // LDS transpose: 4 passes over 32-pixel m-quarters.
        float* tf = (float*)smem;
        const int nc = n0 - 256;
        #pragma unroll
        for (int mq = 0; mq < 4; ++mq) {
            __syncthreads();
            if ((wid & 1) == (mq >> 1)) {
                #pragma unroll
                for (int jj = 0; jj < 2; ++jj) {
                    int j = (mq & 1) * 2 + jj;
                    int ml = j * 16 + l15 - (mq & 1) * 32;   // 0..31
                    #pragma unroll
                    for (int i = 0; i < 4; ++i) {
                        int nl = wn + i * 16 + quad * 4;
                        #pragma unroll
                        for (int r = 0; r < 4; ++r)
                            tf[ml * 132 + nl + r] = acc[i][j][r] + bfv[nc + nl + r];
                    }
                }
            }
            __syncthreads();
            int mm = tid >> 3;            // 0..31
            int c8 = tid & 7;
            float* dst = procT + ((size_t)b * HW0 + m0 + mq * 32 + mm) * CH + nc;
            #pragma unroll
            for (int k = 0; k < 4; ++k) {
                int col = c8 * 4 + k * 32;
                *(float4*)(dst + col) = *(const float4*)&tf[mm * 132 + col];
            }
        }
    }
}

// ---------------------------------------------------------------------------
// K2: MFMA GEMM + fused upsample epilogue + FUSED low-transpose:
//   val[n, y, x] = relu( A2[n,:].low[:, y, x] + up2x(T)[n,y,x] + b1[n] )
// X staged directly from f32 low (NCHW) with in-LDS transpose+bf16-convert —
// ktrans_low eliminated.  Written TRANSPOSED as off_featT[b][pix][256] bf16.
// Flat grid 2048: b = bid&7 (XCD affinity; the 2 n-blocks of a row are
// adjacent on one XCD -> low row read once from HBM, 2nd pass L2).
// ---------------------------------------------------------------------------
__global__ __launch_bounds__(256) void k2_mfma(
    const float* __restrict__ low,             // [B][256][128][128] f32
    const unsigned short* __restrict__ A2,     // [256][256]
    const float* __restrict__ b1, const float* __restrict__ T,
    unsigned short* __restrict__ off_featT)
{
    const int bid = blockIdx.x;
    const int b  = bid & 7;
    const int q  = bid >> 3;            // 0..255
    const int y  = q >> 1;              // 0..127
    const int n0 = (q & 1) * 128;
    const int tid = threadIdx.x;
    __shared__ unsigned short smem[2 * 128 * 40];
    unsigned short* As = smem;
    unsigned short* Xs = smem + 128 * 40;
    const int lane = tid & 63, wid = tid >> 6;
    const int wn = (wid >> 1) * 64, wm = (wid & 1) * 64;
    const int l15 = lane & 15, quad = lane >> 4;

    floatx4 acc[4][4];
    #pragma unroll
    for (int i = 0; i < 4; ++i)
        #pragma unroll
        for (int j = 0; j < 4; ++j)
            acc[i][j] = (floatx4){0.f, 0.f, 0.f, 0.f};

    const float* Lg = low + (size_t)b * CH * HW2 + (size_t)y * 128;
    const int spx = tid & 127, sg = tid >> 7;

    for (int k0 = 0; k0 < 256; k0 += 32) {
        for (int c = tid; c < 512; c += 256) {
            int row = c >> 2, kc = (c & 3) * 8;
            *(u16x8*)&As[row * 40 + kc] =
                *(const u16x8*)(A2 + (size_t)(n0 + row) * CH + k0 + kc);
        }
        // X staging: 4 consecutive channels per thread-task, coalesced f32
        // rows (lanes = contiguous px), pack to bf16x4, ds_write_b64.
        #pragma unroll
        for (int itc = 0; itc < 4; ++itc) {
            int cg4 = sg + itc * 2;            // 0..7
            const float* lp = Lg + (size_t)(k0 + cg4 * 4) * HW2 + spx;
            float v0 = lp[0];
            float v1 = lp[HW2];
            float v2 = lp[2 * HW2];
            float v3 = lp[3 * HW2];
            u16x4 o = { f2bf(v0), f2bf(v1), f2bf(v2), f2bf(v3) };
            *(u16x4*)&Xs[spx * 40 + cg4 * 4] = o;
        }
        __syncthreads();
        short8 af[4], bfr[4];
        #pragma unroll
        for (int i = 0; i < 4; ++i)
            af[i] = *(const short8*)&As[(wn + i * 16 + l15) * 40 + quad * 8];
        #pragma unroll
        for (int j = 0; j < 4; ++j)
            bfr[j] = *(const short8*)&Xs[(wm + j * 16 + l15) * 40 + quad * 8];
        #pragma unroll
        for (int i = 0; i < 4; ++i)
            #pragma unroll
            for (int j = 0; j < 4; ++j)
                acc[i][j] = __builtin_amdgcn_mfma_f32_16x16x32_bf16(
                    af[i], bfr[j], acc[i][j], 0, 0, 0);
        __syncthreads();
    }

    // epilogue: upsample taps. y uniform per block.
    int hk = y >> 1;
    int yA, yB; float wyA, wyB;
    if (y & 1) { yA = hk; yB = min(hk + 1, 63); wyA = 0.75f; wyB = 0.25f; }
    else       { yB = hk; yA = max(hk - 1, 0);  wyA = 0.25f; wyB = 0.75f; }

    int xA[4], xB[4]; float wxA[4], wxB[4];
    #pragma unroll
    for (int j = 0; j < 4; ++j) {
        int x = wm + j * 16 + l15;
        int xk = x >> 1;
        if (x & 1) { xA[j] = xk; xB[j] = min(xk + 1, 63); wxA[j] = 0.75f; wxB[j] = 0.25f; }
        else       { xB[j] = xk; xA[j] = max(xk - 1, 0);  wxA[j] = 0.25f; wxB[j] = 0.75f; }
    }

    #pragma unroll
    for (int i = 0; i < 4; ++i) {
        int nb = n0 + wn + i * 16 + quad * 4;
        #pragma unroll
        for (int r = 0; r < 4; ++r) {
            int n = nb + r;
            const float* tb  = T + ((size_t)b * CH + n) * HW0;
            const float* trA = tb + yA * 64;
            const float* trB = tb + yB * 64;
            float bias = b1[n];
            #pragma unroll
            for (int j = 0; j < 4; ++j) {
                float up = wyA * (wxA[j] * trA[xA[j]] + wxB[j] * trA[xB[j]])
                         + wyB * (wxA[j] * trB[xA[j]] + wxB[j] * trB[xB[j]]);
                acc[i][j][r] = fmaxf(acc[i][j][r] + up + bias, 0.0f);
            }
        }
    }

    // LDS transpose: two passes of [64 x][128 n], write k-contiguous bf16.
    unsigned short (*tile)[136] = (unsigned short (*)[136])smem;
    for (int xh = 0; xh < 2; ++xh) {
        __syncthreads();
        if ((wid & 1) == xh) {
            #pragma unroll
            for (int i = 0; i < 4; ++i) {
                int nc = wn + i * 16 + quad * 4;
                #pragma unroll
                for (int j = 0; j < 4; ++j) {
                    int xr = j * 16 + l15;
                    unsigned int lo = (unsigned int)f2bf(acc[i][j][0])
                                    | ((unsigned int)f2bf(acc[i][j][1]) << 16);
                    unsigned int hi = (unsigned int)f2bf(acc[i][j][2])
                                    | ((unsigned int)f2bf(acc[i][j][3]) << 16);
                    *(unsigned int*)&tile[xr][nc]     = lo;
                    *(unsigned int*)&tile[xr][nc + 2] = hi;
                }
            }
        }
        __syncthreads();
        for (int c = tid; c < 1024; c += 256) {
            int xr = c >> 4, nc = (c & 15) * 8;
            u16x8 v = *(u16x8*)&tile[xr][nc];
            *(u16x8*)(off_featT +
                ((size_t)b * HW2 + (size_t)y * 128 + xh * 64 + xr) * CH + n0 + nc) = v;
        }
    }
}

// ---------------------------------------------------------------------------
// K3: offsets = conv3x3(off_featT, W3p) via MFMA, LDS-staged.
// Block = 32 out px (b, y, xq).  Stage 3 rows x 34 px x full 256 ch into LDS
// (52 KB, XOR-swizzled 16B slots -> conflict-free ds_read_b128; staging loads
// are fully-contiguous 512B px rows).  4 waves split K (64 ch each, W3p
// frags in registers, 36 MFMA/wave), then 4-way f32 LDS reduction.
// Flat grid 4096: b = bid&7 (XCD streams its own 8MB batch; row overlap and
// the 3x tap re-reads come from L2).
// ---------------------------------------------------------------------------
__global__ __launch_bounds__(256) void k3_mfma(
    const unsigned short* __restrict__ offT,   // [B][16384][256] bf16
    const unsigned short* __restrict__ W3p,    // [9][16][256] bf16
    float* __restrict__ offs)
{
    const int bid = blockIdx.x;
    const int b  = bid & 7;
    const int q  = bid >> 3;       // 0..511
    const int y  = q >> 2;         // 0..127
    const int xq = q & 3;          // 32-px quarter
    const int tid = threadIdx.x;
    const int lane = tid & 63, w = tid >> 6;
    const int l15 = lane & 15, quad = lane >> 4;

    __shared__ __attribute__((aligned(16))) unsigned short st[3 * 34 * 256];

    // B fragments: wave w covers ch [w*64, w*64+64)
    short8 bw[9][2];
    #pragma unroll
    for (int t = 0; t < 9; ++t)
        #pragma unroll
        for (int k0 = 0; k0 < 2; ++k0)
            bw[t][k0] = *(const short8*)(W3p + (size_t)(t * 16 + l15) * CH
                                         + w * 64 + k0 * 32 + quad * 8);

    // stage 3 rows x 34 px x 256 ch, zero-padded edges, swizzled 16B slots
    const unsigned short* src = offT + (size_t)b * HW2 * CH;
    for (int it = tid; it < 3264; it += 256) {     // 3*34*32 16B tasks
        int s   = it & 31;
        int px  = (it >> 5) % 34;
        int row = it / (34 * 32);
        int gy = y - 1 + row;
        int gx = xq * 32 - 1 + px;
        u16x8 v = (u16x8){0, 0, 0, 0, 0, 0, 0, 0};
        if ((unsigned)gy < 128u && (unsigned)gx < 128u)
            v = *(const u16x8*)(src + ((size_t)gy * 128 + gx) * CH + s * 8);
        *(u16x8*)&st[(row * 34 + px) * 256 + ((s ^ (px & 7)) * 8)] = v;
    }
    __syncthreads();

    floatx4 acc[2];
    acc[0] = (floatx4){0.f, 0.f, 0.f, 0.f};
    acc[1] = (floatx4){0.f, 0.f, 0.f, 0.f};

    #pragma unroll
    for (int k0 = 0; k0 < 2; ++k0) {
        #pragma unroll
        for (int t = 0; t < 9; ++t) {
            const int row = t / 3, dxi = t % 3;
            const int srd = w * 8 + k0 * 4 + quad;
            #pragma unroll
            for (int j = 0; j < 2; ++j) {
                int px = j * 16 + l15 + dxi;        // 0..33
                short8 a = *(const short8*)&st[(row * 34 + px) * 256
                                               + ((srd ^ (px & 7)) * 8)];
                acc[j] = __builtin_amdgcn_mfma_f32_16x16x32_bf16(
                    a, bw[t][k0], acc[j], 0, 0, 0);
            }
        }
    }

    __syncthreads();
    float* red = (float*)st;            // [4 waves][32 px][16 oc]
    #pragma unroll
    for (int j = 0; j < 2; ++j)
        #pragma unroll
        for (int r = 0; r < 4; ++r)
            red[(w * 32 + j * 16 + quad * 4 + r) * 16 + l15] = acc[j][r];
    __syncthreads();

    const int oc = tid >> 5, px = tid & 31;   // 8 oc x 32 px = 256 threads
    float s0 = red[px * 16 + oc]        + red[(32 + px) * 16 + oc]
             + red[(64 + px) * 16 + oc] + red[(96 + px) * 16 + oc];
    offs[((size_t)b * 8 + oc) * HW2 + (size_t)y * 128 + xq * 32 + px] = s0;
}

// ---------------------------------------------------------------------------
// K4: deformable 4-point border-clamped bilinear sample of procT, averaged.
// Each lane loads float4 (4 channels) -> one wave covers all 256 ch per tap.
// ---------------------------------------------------------------------------
__global__ __launch_bounds__(256) void k4_sample(
    const float* __restrict__ offs, const float* __restrict__ b2v,
    const float* __restrict__ procT, float* __restrict__ out)
{
    const int blk = blockIdx.x;
    const int b  = blk & 7;
    const int r  = blk >> 3;       // 0..255
    const int y  = r >> 1;
    const int xh = r & 1;          // 64-px half row
    const int tid = threadIdx.x;
    const int lane = tid & 63, w = tid >> 6;

    __shared__ int2   sp_i[4][64];     // [p][px]: gather idx, pack(dxo,dyo)
    __shared__ float4 sp_w[4][64];     // [p][px]: 0.25*bilinear weights
    __shared__ float  tile[4][8 * 260];

    if (tid < 64) {
        int x = xh * 64 + tid;
        float gxb = (2.0f * x) / 127.0f - 1.0f;
        float gyb = (2.0f * y) / 127.0f - 1.0f;
        const float* ob = offs + (size_t)b * 8 * HW2 + y * 128 + x;
        #pragma unroll
        for (int p = 0; p < 4; ++p) {
            float ox = ob[(2 * p) * HW2] + b2v[2 * p];
            float oy = ob[(2 * p + 1) * HW2] + b2v[2 * p + 1];
            float gx = gxb + ox * (2.0f / 128.0f);
            float gy = gyb + oy * (2.0f / 128.0f);
            float gxp = fminf(fmaxf((gx + 1.0f) * 32.0f - 0.5f, 0.0f), 63.0f);
            float gyp = fminf(fmaxf((gy + 1.0f) * 32.0f - 0.5f, 0.0f), 63.0f);
            float x0f = floorf(gxp), y0f = floorf(gyp);
            int x0 = (int)x0f, y0 = (int)y0f;
            int idx = (y0 * 64 + x0) * 256;          // float offset into procT[b]
            int dxo = (x0 < 63) ? 256 : 0;           // +1 px in x
            int dyo = (y0 < 63) ? 16384 : 0;         // +1 px in y (64*256)
            float fx = gxp - x0f, fy = gyp - y0f;
            float ex = 1.0f - fx, ey = 1.0f - fy;
            sp_i[p][tid] = make_int2(idx, dxo | (dyo << 16));
            sp_w[p][tid] = make_float4(0.25f * ex * ey, 0.25f * fx * ey,
                                       0.25f * ex * fy, 0.25f * fx * fy);
        }
    }
    __syncthreads();

    const float* P = procT + (size_t)b * HW0 * CH + lane * 4;
    float* tw = &tile[w][0];
    float* outb = out + (size_t)b * CH * HW2 + (size_t)y * 128 + xh * 64 + w * 16;

    for (int c8 = 0; c8 < 2; ++c8) {
        #pragma unroll
        for (int i = 0; i < 8; ++i) {
            int lpx = w * 16 + c8 * 8 + i;     // local px, uniform per wave
            float4 a = make_float4(0.f, 0.f, 0.f, 0.f);
            #pragma unroll
            for (int p = 0; p < 4; ++p) {
                int2 si = sp_i[p][lpx];
                float4 sw = sp_w[p][lpx];
                int dxo = si.y & 0xFFFF, dyo = si.y >> 16;
                const float* qp = P + si.x;
                float4 v00 = *(const float4*)(qp);
                float4 v01 = *(const float4*)(qp + dxo);
                float4 v10 = *(const float4*)(qp + dyo);
                float4 v11 = *(const float4*)(qp + dyo + dxo);
                a.x += sw.x * v00.x + sw.y * v01.x + sw.z * v10.x + sw.w * v11.x;
                a.y += sw.x * v00.y + sw.y * v01.y + sw.z * v10.y + sw.w * v11.y;
                a.z += sw.x * v00.z + sw.y * v01.z + sw.z * v10.z + sw.w * v11.z;
                a.w += sw.x * v00.w + sw.y * v01.w + sw.z * v10.w + sw.w * v11.w;
            }
            *(float4*)&tw[i * 260 + lane * 4] = a;
        }
        __syncthreads();
        #pragma unroll
        for (int g = 0; g < 32; ++g) {
            int c   = g * 8 + (lane >> 3);
            int pxl = lane & 7;
            outb[(size_t)c * HW2 + c8 * 8 + pxl] = tw[pxl * 260 + c];
        }
        __syncthreads();
    }
}

// ---------------------------------------------------------------------------
extern "C" void kernel_launch(void* const* d_in, const int* in_sizes, int n_in,
                              void* d_out, int out_size, void* d_ws, size_t ws_size,
                              hipStream_t stream) {
    const float* high = (const float*)d_in[0];
    const float* low  = (const float*)d_in[1];
    const float* W1   = (const float*)d_in[2];
    const float* b1   = (const float*)d_in[3];
    const float* W2v  = (const float*)d_in[4];
    const float* b2v  = (const float*)d_in[5];
    const float* Wf   = (const float*)d_in[6];
    const float* bfv  = (const float*)d_in[7];
    float* out = (float*)d_out;
    float* ws  = (float*)d_ws;

    // ws layout (floats):
    float* T     = ws;                       // 8*256*4096  = 8388608
    float* procT = ws + 8388608;             // 8388608  ([B][4096][256])
    float* offs  = ws + 16777216;            // 1048576
    unsigned short* highT = (unsigned short*)(ws + 17825792);  // 8388608 shorts
    unsigned short* A1 = highT + 8388608;   // 131072 shorts
    unsigned short* A2 = A1 + 131072;       // 65536 shorts  (total ~88.5 MB)

    // W3p reuses highT's storage — written only AFTER k1 (highT dead by then).
    unsigned short* W3p = highT;            // 36864 shorts

    // d_out (33554432 floats = 134 MB) doubles as scratch (upper half):
    unsigned short* off_featT = ((unsigned short*)out) + 33554432;

    // transpose+convert high to bf16 [b][m][256]  (low fused into k2)
    ktrans<<<dim3(32, 8, NB), 256, 0, stream>>>(high, highT, HW0);
    kwconv<<<dim3(512), 256, 0, stream>>>(W1, Wf, A1, A2);

    // T = W1a@high (row-major), procT = (Wf@high + bf) transposed
    k1_mfma<<<dim3(1024), 256, 0, stream>>>(highT, A1, bfv, T, procT);
    // pack conv3x3 weights (over dead highT region)
    kwpack<<<dim3(144), 256, 0, stream>>>(W2v, W3p);
    // off_featT = relu(W1b@low + up2x(T) + b1)  (f32 low staged in-kernel)
    k2_mfma<<<dim3(2048), 256, 0, stream>>>(low, A2, b1, T, off_featT);
    // offs = conv3x3(off_featT, W2)  (MFMA, LDS-staged, XCD-affine)
    k3_mfma<<<dim3(4096), 256, 0, stream>>>(off_featT, W3p, offs);
    // out = mean over 4 deformable bilinear samples of procT
    k4_sample<<<dim3(2048), 256, 0, stream>>>(offs, b2v, procT, out);
}

// Round 6
// 503.634 us; speedup vs baseline: 1.3514x; 1.0167x over previous
//
#include <hip/hip_runtime.h>
#include <stdint.h>

// Problem constants: B=8, Cin=Cout=256, H=W=64, H2=W2=128, P=4 points.
#define NB   8
#define CH   256
#define HW0  4096    // 64*64
#define HW2  16384   // 128*128

typedef __attribute__((ext_vector_type(8))) short short8;
typedef __attribute__((ext_vector_type(8))) unsigned short u16x8;
typedef __attribute__((ext_vector_type(4))) unsigned short u16x4;
typedef __attribute__((ext_vector_type(4))) float floatx4;

__device__ inline unsigned short f2bf(float f) {
    union { float f; uint32_t u; } v; v.f = f;
    return (unsigned short)((v.u + 0x7FFFu + ((v.u >> 16) & 1u)) >> 16);
}
__device__ inline float bf2f(unsigned short h) {
    union { uint32_t u; float f; } v; v.u = ((uint32_t)h) << 16;
    return v.f;
}

// ---------------------------------------------------------------------------
// ktrans: [B][256][M] f32  ->  [B][M][256] bf16   (transpose + convert)
// Used only for high_feat (low transpose fused into k2).
// ---------------------------------------------------------------------------
__global__ __launch_bounds__(256) void ktrans(const float* __restrict__ src,
        unsigned short* __restrict__ dst, int M) {
    const int b = blockIdx.z, k0 = blockIdx.y * 32, m0 = blockIdx.x * 128;
    const int tid = threadIdx.x;
    __shared__ unsigned short tile[32][132];
    const float* s = src + ((size_t)b * CH + k0) * M + m0;
    for (int c = tid; c < 1024; c += 256) {
        int kk = c >> 5, mm = (c & 31) * 4;
        float4 v = *(const float4*)(s + (size_t)kk * M + mm);
        u16x4 o = { f2bf(v.x), f2bf(v.y), f2bf(v.z), f2bf(v.w) };
        *(u16x4*)&tile[kk][mm] = o;
    }
    __syncthreads();
    unsigned short* d = dst + ((size_t)b * M + m0) * CH + k0;
    for (int c = tid; c < 512; c += 256) {
        int mm = c >> 2, kc = (c & 3) * 8;
        u16x8 v;
        #pragma unroll
        for (int i = 0; i < 8; ++i) v[i] = tile[kc + i][mm];
        *(u16x8*)(d + (size_t)mm * CH + kc) = v;
    }
}

// ---------------------------------------------------------------------------
// kwconv: pack weights to bf16.  A1[512][256]: rows 0-255 = W1a, 256-511 = Wf.
// A2[256][256] = W1b.
// ---------------------------------------------------------------------------
__global__ __launch_bounds__(256) void kwconv(const float* __restrict__ W1,
        const float* __restrict__ Wf, unsigned short* __restrict__ A1,
        unsigned short* __restrict__ A2) {
    int i = blockIdx.x * 256 + threadIdx.x;
    if (i < 512 * 256) {
        int n = i >> 8, k = i & 255;
        float v = (n < 256) ? W1[n * 512 + k] : Wf[(size_t)(n - 256) * 256 + k];
        A1[i] = f2bf(v);
    }
    if (i < 256 * 256) {
        int n = i >> 8, k = i & 255;
        A2[i] = f2bf(W1[n * 512 + 256 + k]);
    }
}

// ---------------------------------------------------------------------------
// kwpack: W2 [8][256][3][3] f32 -> W3p [9 taps][16 o (8 padded)][256 ci] bf16
// Launched AFTER k1 (reuses the then-dead highT buffer).
// ---------------------------------------------------------------------------
__global__ __launch_bounds__(256) void kwpack(const float* __restrict__ W2v,
        unsigned short* __restrict__ W3p) {
    int i = blockIdx.x * 256 + threadIdx.x;   // 9*16*256 = 36864
    if (i >= 9 * 16 * 256) return;
    int ci = i & 255, o = (i >> 8) & 15, t = i >> 12;
    float v = (o < 8) ? W2v[((size_t)o * 256 + ci) * 9 + t] : 0.0f;
    W3p[i] = f2bf(v);
}

// ---------------------------------------------------------------------------
// K1: dual MFMA GEMM:  D[n,m] = A1[n,:] . highT[m,:]   (k-contig both sides)
//   n<256 -> T[b][n][m]  ; n>=256 -> procT[b][m][n-256] + bf (LDS transpose)
// Flat grid 1024: b = bid&7 (XCD affinity: highT[b] = 2MB fits one XCD L2).
// ---------------------------------------------------------------------------
__global__ __launch_bounds__(256) void k1_mfma(
    const unsigned short* __restrict__ highT,  // [B][4096][256]
    const unsigned short* __restrict__ A1,     // [512][256]
    const float* __restrict__ bfv,
    float* __restrict__ T, float* __restrict__ procT)
{
    const int bid = blockIdx.x;
    const int b  = bid & 7;
    const int q  = bid >> 3;            // 0..127
    const int m0 = (q & 31) * 128;      // over 4096
    const int n0 = (q >> 5) * 128;      // over 512
    const int tid = threadIdx.x;
    __shared__ __attribute__((aligned(16))) unsigned short smem[2 * 128 * 40];
    unsigned short* As = smem;
    unsigned short* Xs = smem + 128 * 40;
    const int lane = tid & 63, wid = tid >> 6;
    const int wn = (wid >> 1) * 64, wm = (wid & 1) * 64;
    const int l15 = lane & 15, quad = lane >> 4;

    floatx4 acc[4][4];
    #pragma unroll
    for (int i = 0; i < 4; ++i)
        #pragma unroll
        for (int j = 0; j < 4; ++j)
            acc[i][j] = (floatx4){0.f, 0.f, 0.f, 0.f};

    const unsigned short* Xg = highT + ((size_t)b * HW0 + m0) * CH;

    for (int k0 = 0; k0 < 256; k0 += 32) {
        for (int c = tid; c < 512; c += 256) {
            int row = c >> 2, kc = (c & 3) * 8;
            *(u16x8*)&As[row * 40 + kc] =
                *(const u16x8*)(A1 + (size_t)(n0 + row) * CH + k0 + kc);
            *(u16x8*)&Xs[row * 40 + kc] =
                *(const u16x8*)(Xg + (size_t)row * CH + k0 + kc);
        }
        __syncthreads();
        short8 af[4], bfr[4];
        #pragma unroll
        for (int i = 0; i < 4; ++i)
            af[i] = *(const short8*)&As[(wn + i * 16 + l15) * 40 + quad * 8];
        #pragma unroll
        for (int j = 0; j < 4; ++j)
            bfr[j] = *(const short8*)&Xs[(wm + j * 16 + l15) * 40 + quad * 8];
        #pragma unroll
        for (int i = 0; i < 4; ++i)
            #pragma unroll
            for (int j = 0; j < 4; ++j)
                acc[i][j] = __builtin_amdgcn_mfma_f32_16x16x32_bf16(
                    af[i], bfr[j], acc[i][j], 0, 0, 0);
        __syncthreads();
    }

    if (n0 < 256) {
        #pragma unroll
        for (int i = 0; i < 4; ++i) {
            int nb = n0 + wn + i * 16 + quad * 4;
            #pragma unroll
            for (int r = 0; r < 4; ++r) {
                int n = nb + r;
                #pragma unroll
                for (int j = 0; j < 4; ++j) {
                    int m = m0 + wm + j * 16 + l15;
                    T[((size_t)b * CH + n) * HW0 + m] = acc[i][j][r];
                }
            }
        }
    } else {
        // LDS transpose: 4 passes over 32-pixel m-quarters.
        float* tf = (float*)smem;
        const int nc = n0 - 256;
        #pragma unroll
        for (int mq = 0; mq < 4; ++mq) {
            __syncthreads();
            if ((wid & 1) == (mq >> 1)) {
                #pragma unroll
                for (int jj = 0; jj < 2; ++jj) {
                    int j = (mq & 1) * 2 + jj;
                    int ml = j * 16 + l15 - (mq & 1) * 32;   // 0..31
                    #pragma unroll
                    for (int i = 0; i < 4; ++i) {
                        int nl = wn + i * 16 + quad * 4;
                        #pragma unroll
                        for (int r = 0; r < 4; ++r)
                            tf[ml * 132 + nl + r] = acc[i][j][r] + bfv[nc + nl + r];
                    }
                }
            }
            __syncthreads();
            int mm = tid >> 3;            // 0..31
            int c8 = tid & 7;
            float* dst = procT + ((size_t)b * HW0 + m0 + mq * 32 + mm) * CH + nc;
            #pragma unroll
            for (int k = 0; k < 4; ++k) {
                int col = c8 * 4 + k * 32;
                *(float4*)(dst + col) = *(const float4*)&tf[mm * 132 + col];
            }
        }
    }
}

// ---------------------------------------------------------------------------
// K2: MFMA GEMM + fused upsample epilogue + FUSED low-transpose:
//   val[n, y, x] = relu( A2[n,:].low[:, y, x] + up2x(T)[n,y,x] + b1[n] )
// Staging v2: conflict-free 16B LDS writes (wave w = ch-slot w, px = lane;
// 20-dword row stride tiles all 32 banks) + double-buffered register prefetch
// (next k-step's A/X loads issued before the MFMA phase, pack+write after the
// next barrier — HBM/L2 latency hides under MFMA).
// Flat grid 2048: b = bid&7 (XCD affinity).
// ---------------------------------------------------------------------------
__global__ __launch_bounds__(256) void k2_mfma(
    const float* __restrict__ low,             // [B][256][128][128] f32
    const unsigned short* __restrict__ A2,     // [256][256]
    const float* __restrict__ b1, const float* __restrict__ T,
    unsigned short* __restrict__ off_featT)
{
    const int bid = blockIdx.x;
    const int b  = bid & 7;
    const int q  = bid >> 3;            // 0..255
    const int y  = q >> 1;              // 0..127
    const int n0 = (q & 1) * 128;
    const int tid = threadIdx.x;
    __shared__ unsigned short smem[2 * 128 * 40];
    unsigned short* As = smem;
    unsigned short* Xs = smem + 128 * 40;
    const int lane = tid & 63, wid = tid >> 6;
    const int wn = (wid >> 1) * 64, wm = (wid & 1) * 64;
    const int l15 = lane & 15, quad = lane >> 4;

    // staging roles:
    //   A: wave-pairs -> 64 consecutive n-rows, fixed 16B k-slot (2 per thread)
    //   X: wave w -> ch-slot w (8 ch), px = lane (+64), 256B-coalesced loads
    const int rowA = lane + (wid & 1) * 64;
    const int slA  = wid >> 1;                 // slots slA and slA+2
    const float* Lg = low + ((size_t)b * CH + wid * 8) * HW2
                      + (size_t)y * 128 + lane;

    floatx4 acc[4][4];
    #pragma unroll
    for (int i = 0; i < 4; ++i)
        #pragma unroll
        for (int j = 0; j < 4; ++j)
            acc[i][j] = (floatx4){0.f, 0.f, 0.f, 0.f};

    u16x8 aR[2];
    float xR[2][8];

    // prologue: load k0 = 0 into registers
    #pragma unroll
    for (int i = 0; i < 2; ++i)
        aR[i] = *(const u16x8*)(A2 + (size_t)(n0 + rowA) * CH + (slA + i * 2) * 8);
    #pragma unroll
    for (int i = 0; i < 2; ++i)
        #pragma unroll
        for (int c = 0; c < 8; ++c)
            xR[i][c] = Lg[(size_t)c * HW2 + i * 64];

    for (int k0 = 0; k0 < 256; k0 += 32) {
        __syncthreads();        // previous tile's frag reads done
        #pragma unroll
        for (int i = 0; i < 2; ++i)
            *(u16x8*)&As[rowA * 40 + (slA + i * 2) * 8] = aR[i];
        #pragma unroll
        for (int i = 0; i < 2; ++i) {
            u16x8 o = { f2bf(xR[i][0]), f2bf(xR[i][1]), f2bf(xR[i][2]),
                        f2bf(xR[i][3]), f2bf(xR[i][4]), f2bf(xR[i][5]),
                        f2bf(xR[i][6]), f2bf(xR[i][7]) };
            *(u16x8*)&Xs[(lane + i * 64) * 40 + wid * 8] = o;
        }
        __syncthreads();
        if (k0 + 32 < 256) {    // prefetch next k-step (overlaps MFMA below)
            #pragma unroll
            for (int i = 0; i < 2; ++i)
                aR[i] = *(const u16x8*)(A2 + (size_t)(n0 + rowA) * CH
                                        + k0 + 32 + (slA + i * 2) * 8);
            #pragma unroll
            for (int i = 0; i < 2; ++i)
                #pragma unroll
                for (int c = 0; c < 8; ++c)
                    xR[i][c] = Lg[(size_t)(k0 + 32 + c) * HW2 + i * 64];
        }
        short8 af[4], bfr[4];
        #pragma unroll
        for (int i = 0; i < 4; ++i)
            af[i] = *(const short8*)&As[(wn + i * 16 + l15) * 40 + quad * 8];
        #pragma unroll
        for (int j = 0; j < 4; ++j)
            bfr[j] = *(const short8*)&Xs[(wm + j * 16 + l15) * 40 + quad * 8];
        #pragma unroll
        for (int i = 0; i < 4; ++i)
            #pragma unroll
            for (int j = 0; j < 4; ++j)
                acc[i][j] = __builtin_amdgcn_mfma_f32_16x16x32_bf16(
                    af[i], bfr[j], acc[i][j], 0, 0, 0);
    }

    // epilogue: upsample taps. y uniform per block.
    int hk = y >> 1;
    int yA, yB; float wyA, wyB;
    if (y & 1) { yA = hk; yB = min(hk + 1, 63); wyA = 0.75f; wyB = 0.25f; }
    else       { yB = hk; yA = max(hk - 1, 0);  wyA = 0.25f; wyB = 0.75f; }

    int xA[4], xB[4]; float wxA[4], wxB[4];
    #pragma unroll
    for (int j = 0; j < 4; ++j) {
        int x = wm + j * 16 + l15;
        int xk = x >> 1;
        if (x & 1) { xA[j] = xk; xB[j] = min(xk + 1, 63); wxA[j] = 0.75f; wxB[j] = 0.25f; }
        else       { xB[j] = xk; xA[j] = max(xk - 1, 0);  wxA[j] = 0.25f; wxB[j] = 0.75f; }
    }

    #pragma unroll
    for (int i = 0; i < 4; ++i) {
        int nb = n0 + wn + i * 16 + quad * 4;
        #pragma unroll
        for (int r = 0; r < 4; ++r) {
            int n = nb + r;
            const float* tb  = T + ((size_t)b * CH + n) * HW0;
            const float* trA = tb + yA * 64;
            const float* trB = tb + yB * 64;
            float bias = b1[n];
            #pragma unroll
            for (int j = 0; j < 4; ++j) {
                float up = wyA * (wxA[j] * trA[xA[j]] + wxB[j] * trA[xB[j]])
                         + wyB * (wxA[j] * trB[xA[j]] + wxB[j] * trB[xB[j]]);
                acc[i][j][r] = fmaxf(acc[i][j][r] + up + bias, 0.0f);
            }
        }
    }

    // LDS transpose: two passes of [64 x][128 n], write k-contiguous bf16.
    unsigned short (*tile)[136] = (unsigned short (*)[136])smem;
    for (int xh = 0; xh < 2; ++xh) {
        __syncthreads();
        if ((wid & 1) == xh) {
            #pragma unroll
            for (int i = 0; i < 4; ++i) {
                int nc = wn + i * 16 + quad * 4;
                #pragma unroll
                for (int j = 0; j < 4; ++j) {
                    int xr = j * 16 + l15;
                    unsigned int lo = (unsigned int)f2bf(acc[i][j][0])
                                    | ((unsigned int)f2bf(acc[i][j][1]) << 16);
                    unsigned int hi = (unsigned int)f2bf(acc[i][j][2])
                                    | ((unsigned int)f2bf(acc[i][j][3]) << 16);
                    *(unsigned int*)&tile[xr][nc]     = lo;
                    *(unsigned int*)&tile[xr][nc + 2] = hi;
                }
            }
        }
        __syncthreads();
        for (int c = tid; c < 1024; c += 256) {
            int xr = c >> 4, nc = (c & 15) * 8;
            u16x8 v = *(u16x8*)&tile[xr][nc];
            *(u16x8*)(off_featT +
                ((size_t)b * HW2 + (size_t)y * 128 + xh * 64 + xr) * CH + n0 + nc) = v;
        }
    }
}

// ---------------------------------------------------------------------------
// K3: offsets = conv3x3(off_featT, W3p) via MFMA, LDS-staged.
// Block = 32 out px (b, y, xq); 3 rows x 34 px x 256 ch staged swizzled;
// 4 waves split K; f32 LDS reduction.  Flat grid 4096: b = bid&7.
// ---------------------------------------------------------------------------
__global__ __launch_bounds__(256) void k3_mfma(
    const unsigned short* __restrict__ offT,   // [B][16384][256] bf16
    const unsigned short* __restrict__ W3p,    // [9][16][256] bf16
    float* __restrict__ offs)
{
    const int bid = blockIdx.x;
    const int b  = bid & 7;
    const int q  = bid >> 3;       // 0..511
    const int y  = q >> 2;         // 0..127
    const int xq = q & 3;          // 32-px quarter
    const int tid = threadIdx.x;
    const int lane = tid & 63, w = tid >> 6;
    const int l15 = lane & 15, quad = lane >> 4;

    __shared__ __attribute__((aligned(16))) unsigned short st[3 * 34 * 256];

    short8 bw[9][2];
    #pragma unroll
    for (int t = 0; t < 9; ++t)
        #pragma unroll
        for (int k0 = 0; k0 < 2; ++k0)
            bw[t][k0] = *(const short8*)(W3p + (size_t)(t * 16 + l15) * CH
                                         + w * 64 + k0 * 32 + quad * 8);

    const unsigned short* src = offT + (size_t)b * HW2 * CH;
    for (int it = tid; it < 3264; it += 256) {     // 3*34*32 16B tasks
        int s   = it & 31;
        int px  = (it >> 5) % 34;
        int row = it / (34 * 32);
        int gy = y - 1 + row;
        int gx = xq * 32 - 1 + px;
        u16x8 v = (u16x8){0, 0, 0, 0, 0, 0, 0, 0};
        if ((unsigned)gy < 128u && (unsigned)gx < 128u)
            v = *(const u16x8*)(src + ((size_t)gy * 128 + gx) * CH + s * 8);
        *(u16x8*)&st[(row * 34 + px) * 256 + ((s ^ (px & 7)) * 8)] = v;
    }
    __syncthreads();

    floatx4 acc[2];
    acc[0] = (floatx4){0.f, 0.f, 0.f, 0.f};
    acc[1] = (floatx4){0.f, 0.f, 0.f, 0.f};

    #pragma unroll
    for (int k0 = 0; k0 < 2; ++k0) {
        #pragma unroll
        for (int t = 0; t < 9; ++t) {
            const int row = t / 3, dxi = t % 3;
            const int srd = w * 8 + k0 * 4 + quad;
            #pragma unroll
            for (int j = 0; j < 2; ++j) {
                int px = j * 16 + l15 + dxi;        // 0..33
                short8 a = *(const short8*)&st[(row * 34 + px) * 256
                                               + ((srd ^ (px & 7)) * 8)];
                acc[j] = __builtin_amdgcn_mfma_f32_16x16x32_bf16(
                    a, bw[t][k0], acc[j], 0, 0, 0);
            }
        }
    }

    __syncthreads();
    float* red = (float*)st;            // [4 waves][32 px][16 oc]
    #pragma unroll
    for (int j = 0; j < 2; ++j)
        #pragma unroll
        for (int r = 0; r < 4; ++r)
            red[(w * 32 + j * 16 + quad * 4 + r) * 16 + l15] = acc[j][r];
    __syncthreads();

    const int oc = tid >> 5, px = tid & 31;   // 8 oc x 32 px = 256 threads
    float s0 = red[px * 16 + oc]        + red[(32 + px) * 16 + oc]
             + red[(64 + px) * 16 + oc] + red[(96 + px) * 16 + oc];
    offs[((size_t)b * 8 + oc) * HW2 + (size_t)y * 128 + xq * 32 + px] = s0;
}

// ---------------------------------------------------------------------------
// K4: deformable 4-point border-clamped bilinear sample of procT, averaged.
// Each lane loads float4 (4 channels) -> one wave covers all 256 ch per tap.
// ---------------------------------------------------------------------------
__global__ __launch_bounds__(256) void k4_sample(
    const float* __restrict__ offs, const float* __restrict__ b2v,
    const float* __restrict__ procT, float* __restrict__ out)
{
    const int blk = blockIdx.x;
    const int b  = blk & 7;
    const int r  = blk >> 3;       // 0..255
    const int y  = r >> 1;
    const int xh = r & 1;          // 64-px half row
    const int tid = threadIdx.x;
    const int lane = tid & 63, w = tid >> 6;

    __shared__ int2   sp_i[4][64];     // [p][px]: gather idx, pack(dxo,dyo)
    __shared__ float4 sp_w[4][64];     // [p][px]: 0.25*bilinear weights
    __shared__ float  tile[4][8 * 260];

    if (tid < 64) {
        int x = xh * 64 + tid;
        float gxb = (2.0f * x) / 127.0f - 1.0f;
        float gyb = (2.0f * y) / 127.0f - 1.0f;
        const float* ob = offs + (size_t)b * 8 * HW2 + y * 128 + x;
        #pragma unroll
        for (int p = 0; p < 4; ++p) {
            float ox = ob[(2 * p) * HW2] + b2v[2 * p];
            float oy = ob[(2 * p + 1) * HW2] + b2v[2 * p + 1];
            float gx = gxb + ox * (2.0f / 128.0f);
            float gy = gyb + oy * (2.0f / 128.0f);
            float gxp = fminf(fmaxf((gx + 1.0f) * 32.0f - 0.5f, 0.0f), 63.0f);
            float gyp = fminf(fmaxf((gy + 1.0f) * 32.0f - 0.5f, 0.0f), 63.0f);
            float x0f = floorf(gxp), y0f = floorf(gyp);
            int x0 = (int)x0f, y0 = (int)y0f;
            int idx = (y0 * 64 + x0) * 256;          // float offset into procT[b]
            int dxo = (x0 < 63) ? 256 : 0;           // +1 px in x
            int dyo = (y0 < 63) ? 16384 : 0;         // +1 px in y (64*256)
            float fx = gxp - x0f, fy = gyp - y0f;
            float ex = 1.0f - fx, ey = 1.0f - fy;
            sp_i[p][tid] = make_int2(idx, dxo | (dyo << 16));
            sp_w[p][tid] = make_float4(0.25f * ex * ey, 0.25f * fx * ey,
                                       0.25f * ex * fy, 0.25f * fx * fy);
        }
    }
    __syncthreads();

    const float* P = procT + (size_t)b * HW0 * CH + lane * 4;
    float* tw = &tile[w][0];
    float* outb = out + (size_t)b * CH * HW2 + (size_t)y * 128 + xh * 64 + w * 16;

    for (int c8 = 0; c8 < 2; ++c8) {
        #pragma unroll
        for (int i = 0; i < 8; ++i) {
            int lpx = w * 16 + c8 * 8 + i;     // local px, uniform per wave
            float4 a = make_float4(0.f, 0.f, 0.f, 0.f);
            #pragma unroll
            for (int p = 0; p < 4; ++p) {
                int2 si = sp_i[p][lpx];
                float4 sw = sp_w[p][lpx];
                int dxo = si.y & 0xFFFF, dyo = si.y >> 16;
                const float* qp = P + si.x;
                float4 v00 = *(const float4*)(qp);
                float4 v01 = *(const float4*)(qp + dxo);
                float4 v10 = *(const float4*)(qp + dyo);
                float4 v11 = *(const float4*)(qp + dyo + dxo);
                a.x += sw.x * v00.x + sw.y * v01.x + sw.z * v10.x + sw.w * v11.x;
                a.y += sw.x * v00.y + sw.y * v01.y + sw.z * v10.y + sw.w * v11.y;
                a.z += sw.x * v00.z + sw.y * v01.z + sw.z * v10.z + sw.w * v11.z;
                a.w += sw.x * v00.w + sw.y * v01.w + sw.z * v10.w + sw.w * v11.w;
            }
            *(float4*)&tw[i * 260 + lane * 4] = a;
        }
        __syncthreads();
        #pragma unroll
        for (int g = 0; g < 32; ++g) {
            int c   = g * 8 + (lane >> 3);
            int pxl = lane & 7;
            outb[(size_t)c * HW2 + c8 * 8 + pxl] = tw[pxl * 260 + c];
        }
        __syncthreads();
    }
}

// ---------------------------------------------------------------------------
extern "C" void kernel_launch(void* const* d_in, const int* in_sizes, int n_in,
                              void* d_out, int out_size, void* d_ws, size_t ws_size,
                              hipStream_t stream) {
    const float* high = (const float*)d_in[0];
    const float* low  = (const float*)d_in[1];
    const float* W1   = (const float*)d_in[2];
    const float* b1   = (const float*)d_in[3];
    const float* W2v  = (const float*)d_in[4];
    const float* b2v  = (const float*)d_in[5];
    const float* Wf   = (const float*)d_in[6];
    const float* bfv  = (const float*)d_in[7];
    float* out = (float*)d_out;
    float* ws  = (float*)d_ws;

    // ws layout (floats):
    float* T     = ws;                       // 8*256*4096  = 8388608
    float* procT = ws + 8388608;             // 8388608  ([B][4096][256])
    float* offs  = ws + 16777216;            // 1048576
    unsigned short* highT = (unsigned short*)(ws + 17825792);  // 8388608 shorts
    unsigned short* A1 = highT + 8388608;   // 131072 shorts
    unsigned short* A2 = A1 + 131072;       // 65536 shorts  (total ~88.5 MB)

    // W3p reuses highT's storage — written only AFTER k1 (highT dead by then).
    unsigned short* W3p = highT;            // 36864 shorts

    // d_out (33554432 floats = 134 MB) doubles as scratch (upper half):
    unsigned short* off_featT = ((unsigned short*)out) + 33554432;

    // transpose+convert high to bf16 [b][m][256]  (low fused into k2)
    ktrans<<<dim3(32, 8, NB), 256, 0, stream>>>(high, highT, HW0);
    kwconv<<<dim3(512), 256, 0, stream>>>(W1, Wf, A1, A2);

    // T = W1a@high (row-major), procT = (Wf@high + bf) transposed
    k1_mfma<<<dim3(1024), 256, 0, stream>>>(highT, A1, bfv, T, procT);
    // pack conv3x3 weights (over dead highT region)
    kwpack<<<dim3(144), 256, 0, stream>>>(W2v, W3p);
    // off_featT = relu(W1b@low + up2x(T) + b1)  (f32 low staged in-kernel)
    k2_mfma<<<dim3(2048), 256, 0, stream>>>(low, A2, b1, T, off_featT);
    // offs = conv3x3(off_featT, W2)  (MFMA, LDS-staged, XCD-affine)
    k3_mfma<<<dim3(4096), 256, 0, stream>>>(off_featT, W3p, offs);
    // out = mean over 4 deformable bilinear samples of procT
    k4_sample<<<dim3(2048), 256, 0, stream>>>(offs, b2v, procT, out);
}